// Round 1
// 1766.941 us; speedup vs baseline: 1.6494x; 1.6494x over previous
//
#include <hip/hip_runtime.h>
#include <hip/hip_bf16.h>
#include <math.h>

typedef long long i64;
typedef __hip_bfloat16 bf16;

#define HW 4096
#define KVC 960
#define BATCH 8

using bf8 = __attribute__((ext_vector_type(8))) short;   // 8 bf16 (4 VGPRs)
using f32x4 = __attribute__((ext_vector_type(4))) float; // MFMA accum

__device__ __forceinline__ float bf2f(unsigned short u) {
    union { unsigned int i; float f; } c; c.i = ((unsigned int)u) << 16; return c.f;
}
__device__ __forceinline__ float tof(bf16 v) { return __bfloat162float(v); }
__device__ __forceinline__ unsigned short f2bs(float f) {
    bf16 h = __float2bfloat16(f); return *reinterpret_cast<unsigned short*>(&h);
}
__device__ __forceinline__ unsigned short tobs(float f) { return f2bs(f); }
__device__ __forceinline__ unsigned short tobs(bf16 v) { return *reinterpret_cast<unsigned short*>(&v); }
__device__ __forceinline__ void store1(float* p, float v) { *p = v; }
__device__ __forceinline__ void store1(bf16* p, float v) { *p = __float2bfloat16(v); }

// async global->LDS, 16B per lane. LDS dest is wave-uniform base + lane*16.
__device__ __forceinline__ void gl_lds16(const void* g, void* l) {
    __builtin_amdgcn_global_load_lds(
        (const __attribute__((address_space(1))) void*)g,
        (__attribute__((address_space(3))) void*)l,
        16, 0, 0);
}

// ---------------------------------------------------------------------------
// MFMA GEMM, all-bf16 operands: C[bz] = alpha * A[bz] * B[bz]^T
// A: (M,K) bf16 row-major (leading dim lda). B: (N,K) bf16 row-major (ldb).
// C: (M,N) fp32 or bf16 (ldc). K % 32 == 0. M,N arbitrary (clamped loads,
// guarded stores). Tile 128x128, BK=32, 256 thr = 4 waves, wave = 64x64 via
// 4x4 mfma_f32_16x16x32_bf16. Staging: global_load_lds dwordx4, linear LDS.
//   lane l of wave w, instr j stages row (j*4+w)*16 + l/4, 16B chunk (l&3).
//   LDS offset = ((j*4+w)*16 + l/4)*64B + (l&3)*16B = base(w,j) + l*16  ✓
// ---------------------------------------------------------------------------
template<typename TC>
__global__ __launch_bounds__(256)
void gemm_bt(const bf16* __restrict__ A, int lda, i64 aBatch,
             const bf16* __restrict__ B, int ldb, i64 bBatch,
             TC* __restrict__ C, int ldc, i64 cBatch,
             int M, int N, int K, float alpha)
{
    __shared__ __align__(16) short As[128 * 32];
    __shared__ __align__(16) short Bs[128 * 32];

    const int bz = blockIdx.z;
    const int m0 = blockIdx.y * 128;
    const int n0 = blockIdx.x * 128;
    const int tid  = threadIdx.x;
    const int lane = tid & 63;
    const int wave = tid >> 6;
    const int wm = (wave & 1) * 64;
    const int wn = (wave >> 1) * 64;
    const int quad = lane >> 4;
    const int l16  = lane & 15;

    const bf16* Ab = A + (i64)bz * aBatch;
    const bf16* Bb = B + (i64)bz * bBatch;

    const int srow = lane >> 2;        // row within 16-row group
    const int scol = (lane & 3) * 8;   // bf16 elems (16B chunk)

    int ar0 = m0 + wave * 16 + srow;       if (ar0 >= M) ar0 = M - 1;
    int ar1 = m0 + 64 + wave * 16 + srow;  if (ar1 >= M) ar1 = M - 1;
    int br0 = n0 + wave * 16 + srow;       if (br0 >= N) br0 = N - 1;
    int br1 = n0 + 64 + wave * 16 + srow;  if (br1 >= N) br1 = N - 1;
    const bf16* pa0 = Ab + (i64)ar0 * lda + scol;
    const bf16* pa1 = Ab + (i64)ar1 * lda + scol;
    const bf16* pb0 = Bb + (i64)br0 * ldb + scol;
    const bf16* pb1 = Bb + (i64)br1 * ldb + scol;

    short* la0 = As + wave * 512;          // bytes: wave*1024
    short* la1 = As + 2048 + wave * 512;   // rows 64..127
    short* lb0 = Bs + wave * 512;
    short* lb1 = Bs + 2048 + wave * 512;

    f32x4 acc[4][4] = {};

    for (int k0 = 0; k0 < K; k0 += 32) {
        gl_lds16(pa0 + k0, la0);
        gl_lds16(pa1 + k0, la1);
        gl_lds16(pb0 + k0, lb0);
        gl_lds16(pb1 + k0, lb1);
        __syncthreads();   // drains vmcnt(0) -> tiles resident

        bf8 af[4], bfr[4];
        #pragma unroll
        for (int mt = 0; mt < 4; ++mt)
            af[mt] = *(const bf8*)(As + (wm + mt * 16 + l16) * 32 + quad * 8);
        #pragma unroll
        for (int nt = 0; nt < 4; ++nt)
            bfr[nt] = *(const bf8*)(Bs + (wn + nt * 16 + l16) * 32 + quad * 8);
        #pragma unroll
        for (int mt = 0; mt < 4; ++mt)
            #pragma unroll
            for (int nt = 0; nt < 4; ++nt)
                acc[mt][nt] = __builtin_amdgcn_mfma_f32_16x16x32_bf16(
                    af[mt], bfr[nt], acc[mt][nt], 0, 0, 0);
        __syncthreads();
    }

    // epilogue: C/D layout col=lane&15, row=quad*4+reg
    const i64 cb = (i64)bz * cBatch;
    #pragma unroll
    for (int mt = 0; mt < 4; ++mt) {
        #pragma unroll
        for (int r = 0; r < 4; ++r) {
            const int row = m0 + wm + mt * 16 + quad * 4 + r;
            if (row >= M) continue;
            const i64 rb = cb + (i64)row * ldc;
            #pragma unroll
            for (int nt = 0; nt < 4; ++nt) {
                const int col = n0 + wn + nt * 16 + l16;
                if (col < N) store1(C + rb + col, alpha * acc[mt][nt][r]);
            }
        }
    }
}

// ---------------------------------------------------------------------------
// Tiled transpose + convert: in (BATCH, C, 4096) T (fp32 or bf16) ->
// out (BATCH, 4096, C) bf16. C % 64 == 0. 64x64 tiles, pad 66 shorts.
// ---------------------------------------------------------------------------
template<typename T>
__global__ __launch_bounds__(256)
void transpose_to_bt(const T* __restrict__ in, bf16* __restrict__ outT, int C)
{
    __shared__ unsigned short t[64][66];
    const int b  = blockIdx.z;
    const int n0 = blockIdx.x * 64;   // HW dim
    const int c0 = blockIdx.y * 64;   // C dim
    const int tx = threadIdx.x & 63, ty = threadIdx.x >> 6;
    const T* ip = in + ((i64)b * C + c0) * (i64)HW + n0;
    #pragma unroll
    for (int i = 0; i < 16; ++i) {
        const int r = ty + i * 4;
        t[r][tx] = tobs(ip[(i64)r * HW + tx]);
    }
    __syncthreads();
    bf16* op = outT + ((i64)b * HW + n0) * (i64)C + c0;
    #pragma unroll
    for (int i = 0; i < 16; ++i) {
        const int r = ty + i * 4;
        *(unsigned short*)(op + (i64)r * C + tx) = t[tx][r];
    }
}

// ---------------------------------------------------------------------------
// One-shot fp32 -> bf16 conversion of all 10 weight tensors into wb.
// element offsets: wmk 0, wmv 921600, wm1..4 @1843200/1847296/1863680/1929216,
// wp1..4 @2191360/2195456/2211840/2277376, total 2539520.
// ---------------------------------------------------------------------------
__global__ __launch_bounds__(256)
void cvt_weights(const float* __restrict__ s0, const float* __restrict__ s1,
                 const float* __restrict__ s2, const float* __restrict__ s3,
                 const float* __restrict__ s4, const float* __restrict__ s5,
                 const float* __restrict__ s6, const float* __restrict__ s7,
                 const float* __restrict__ s8, const float* __restrict__ s9,
                 bf16* __restrict__ wb)
{
    const int i = (blockIdx.x * 256 + threadIdx.x) * 4;
    if (i >= 2539520) return;
    const float* src; int off;
    if      (i <  921600) { src = s0; off = 0;       }
    else if (i < 1843200) { src = s1; off = 921600;  }
    else if (i < 1847296) { src = s2; off = 1843200; }
    else if (i < 1863680) { src = s3; off = 1847296; }
    else if (i < 1929216) { src = s4; off = 1863680; }
    else if (i < 2191360) { src = s5; off = 1929216; }
    else if (i < 2195456) { src = s6; off = 2191360; }
    else if (i < 2211840) { src = s7; off = 2195456; }
    else if (i < 2277376) { src = s8; off = 2211840; }
    else                  { src = s9; off = 2277376; }
    const float4 v = *(const float4*)(src + (i - off));
    ushort4 o;
    o.x = f2bs(v.x); o.y = f2bs(v.y); o.z = f2bs(v.z); o.w = f2bs(v.w);
    *(ushort4*)((unsigned short*)wb + i) = o;
}

// ---------------------------------------------------------------------------
// Depthwise 3x3 SAME, NCHW 64x64 images. fp32 weights, bf16 act in/out.
// ---------------------------------------------------------------------------
__global__ __launch_bounds__(256)
void dw3x3(const bf16* __restrict__ in, const float* __restrict__ w,
           bf16* __restrict__ out, int C)
{
    const int idx = blockIdx.x * 256 + threadIdx.x;
    const int p = idx & 4095;
    const int bch = idx >> 12;
    const int c = bch % C;
    const int x = p & 63, y = p >> 6;
    const float* wp = w + c * 9;
    const bf16* ip = in + (i64)bch * HW;
    float s = 0.f;
    #pragma unroll
    for (int dy = -1; dy <= 1; ++dy) {
        const int yy = y + dy;
        if (yy < 0 || yy > 63) continue;
        #pragma unroll
        for (int dx = -1; dx <= 1; ++dx) {
            const int xx = x + dx;
            if (xx < 0 || xx > 63) continue;
            s = fmaf(wp[(dy+1)*3 + (dx+1)], tof(ip[yy*64 + xx]), s);
        }
    }
    out[idx] = __float2bfloat16(s);
}

// ---------------------------------------------------------------------------
// Grouped 3x3 SAME, groups=C/2. w: (C,2,3,3). Writes into a (totc)-channel
// concat buffer at channel offset cstart.
// ---------------------------------------------------------------------------
__global__ __launch_bounds__(256)
void gconv3x3(const bf16* __restrict__ in, const float* __restrict__ w,
              bf16* __restrict__ out, int C, int totc, int cstart)
{
    const int idx = blockIdx.x * 256 + threadIdx.x;
    const int p = idx & 4095;
    const int bch = idx >> 12;
    const int c = bch % C;
    const int b = bch / C;
    const int x = p & 63, y = p >> 6;
    const float* wp = w + c * 18;
    const bf16* i0 = in + ((i64)b * C + (c & ~1)) * HW;
    float s = 0.f;
    #pragma unroll
    for (int j = 0; j < 2; ++j) {
        #pragma unroll
        for (int dy = -1; dy <= 1; ++dy) {
            const int yy = y + dy;
            if (yy < 0 || yy > 63) continue;
            #pragma unroll
            for (int dx = -1; dx <= 1; ++dx) {
                const int xx = x + dx;
                if (xx < 0 || xx > 63) continue;
                s = fmaf(wp[j*9 + (dy+1)*3 + (dx+1)], tof(i0[(i64)j*HW + yy*64 + xx]), s);
            }
        }
    }
    out[((i64)b * totc + cstart + c) * HW + p] = __float2bfloat16(s);
}

// ---------------------------------------------------------------------------
// Per-row L2 normalize (rows of length 4096) in a (totc)-channel concat
// buffer, bf16 in place. Vectorized ushort4 loads; row cached in registers.
// ---------------------------------------------------------------------------
__global__ __launch_bounds__(256)
void l2norm_rows(bf16* __restrict__ x, int totc, int cstart, int cper)
{
    const int row = blockIdx.x;
    const int b = row / cper, ch = row - b * cper;
    bf16* p = x + ((i64)b * totc + cstart + ch) * (i64)HW;
    ushort4* pv = (ushort4*)p;
    ushort4 v[4];
    float ss = 0.f;
    #pragma unroll
    for (int j = 0; j < 4; ++j) {
        v[j] = pv[threadIdx.x + j * 256];
        const float a0 = bf2f(v[j].x), a1 = bf2f(v[j].y);
        const float a2 = bf2f(v[j].z), a3 = bf2f(v[j].w);
        ss += a0*a0 + a1*a1 + a2*a2 + a3*a3;
    }
    #pragma unroll
    for (int o = 32; o > 0; o >>= 1) ss += __shfl_down(ss, o);
    __shared__ float red[4];
    __shared__ float sinv;
    const int lane = threadIdx.x & 63, wid = threadIdx.x >> 6;
    if (lane == 0) red[wid] = ss;
    __syncthreads();
    if (threadIdx.x == 0) {
        const float t = red[0] + red[1] + red[2] + red[3];
        sinv = 1.0f / fmaxf(sqrtf(t), 1e-12f);
    }
    __syncthreads();
    const float inv = sinv;
    #pragma unroll
    for (int j = 0; j < 4; ++j) {
        ushort4 o;
        o.x = f2bs(bf2f(v[j].x) * inv); o.y = f2bs(bf2f(v[j].y) * inv);
        o.z = f2bs(bf2f(v[j].z) * inv); o.w = f2bs(bf2f(v[j].w) * inv);
        pv[threadIdx.x + j * 256] = o;
    }
}

// ---------------------------------------------------------------------------
// Instance-norm stats over branch slice of attnT (BATCH, 960, 960) fp32.
// Branch br occupies columns [CS[br], CS[br]+CC[br]). Stage 1 partials:
// grid (BATCH, 32, 4); each block sums 30 rows x c cols.
// ---------------------------------------------------------------------------
__global__ __launch_bounds__(256)
void inorm_partial(const float* __restrict__ a, float* __restrict__ part)
{
    const int b = blockIdx.x, ch = blockIdx.y, br = blockIdx.z;
    const int CC[4] = {64, 128, 256, 512};
    const int CS[4] = {0, 64, 192, 448};
    const int c = CC[br], cs = CS[br];
    const int csh = 31 - __clz(c);
    const int cmask = c - 1;
    const float* p = a + (i64)b * (KVC * KVC) + (i64)(ch * 30) * KVC + cs;
    const int tot = 30 * c;
    float s = 0.f, s2 = 0.f;
    for (int i = threadIdx.x; i < tot; i += 256) {
        const float v = p[(i64)(i >> csh) * KVC + (i & cmask)];
        s += v;
        s2 = fmaf(v, v, s2);
    }
    #pragma unroll
    for (int o = 32; o > 0; o >>= 1) { s += __shfl_down(s, o); s2 += __shfl_down(s2, o); }
    __shared__ float r1[4], r2[4];
    const int lane = threadIdx.x & 63, wid = threadIdx.x >> 6;
    if (lane == 0) { r1[wid] = s; r2[wid] = s2; }
    __syncthreads();
    if (threadIdx.x == 0) {
        part[((br * 8 + b) * 32 + ch) * 2 + 0] = r1[0] + r1[1] + r1[2] + r1[3];
        part[((br * 8 + b) * 32 + ch) * 2 + 1] = r2[0] + r2[1] + r2[2] + r2[3];
    }
}

__global__ __launch_bounds__(64)
void inorm_finish(const float* __restrict__ part, float* __restrict__ stats)
{
    const int b = blockIdx.x, br = blockIdx.y;
    const int i = threadIdx.x;
    float s = 0.f, s2 = 0.f;
    if (i < 32) {
        s  = part[((br * 8 + b) * 32 + i) * 2 + 0];
        s2 = part[((br * 8 + b) * 32 + i) * 2 + 1];
    }
    #pragma unroll
    for (int o = 16; o > 0; o >>= 1) { s += __shfl_down(s, o); s2 += __shfl_down(s2, o); }
    if (i == 0) {
        const int CC[4] = {64, 128, 256, 512};
        const float n = (float)(CC[br] * KVC);
        const float mu = s / n;
        const float var = s2 / n - mu * mu;
        stats[(br * 8 + b) * 2 + 0] = mu;
        stats[(br * 8 + b) * 2 + 1] = rsqrtf(var + 1e-5f);
    }
}

// ---------------------------------------------------------------------------
// Column softmax over attnT (BATCH, 960 kv-rows, 960 q-cols) with per-branch
// instance-norm transform; writes probsT bf16 (same layout). Block = 64 cols
// (branch boundaries 64/192/448 are 64-aligned), 960 rows, coalesced.
// ---------------------------------------------------------------------------
__global__ __launch_bounds__(256)
void softmax_cols(const float* __restrict__ a, bf16* __restrict__ p,
                  const float* __restrict__ stats)
{
    const int b  = blockIdx.y;
    const int cb = blockIdx.x * 64;
    const int br = (cb >= 448) ? 3 : (cb >= 192) ? 2 : (cb >= 64) ? 1 : 0;
    const int tx = threadIdx.x & 63, ty = threadIdx.x >> 6;
    const float mu = stats[(br * 8 + b) * 2 + 0];
    const float rs = stats[(br * 8 + b) * 2 + 1];
    const i64 base = (i64)b * (KVC * KVC) + cb + tx;

    float mx = -1e30f;
    for (int r = ty; r < KVC; r += 4)
        mx = fmaxf(mx, a[base + (i64)r * KVC]);
    __shared__ float red[4][64];
    red[ty][tx] = mx;
    __syncthreads();
    mx = fmaxf(fmaxf(red[0][tx], red[1][tx]), fmaxf(red[2][tx], red[3][tx]));
    const float M = (mx - mu) * rs;   // rs > 0: transform is monotone

    float se = 0.f;
    for (int r = ty; r < KVC; r += 4)
        se += __expf((a[base + (i64)r * KVC] - mu) * rs - M);
    __syncthreads();
    red[ty][tx] = se;
    __syncthreads();
    const float S = red[0][tx] + red[1][tx] + red[2][tx] + red[3][tx];
    const float inv = 1.0f / S;

    for (int r = ty; r < KVC; r += 4) {
        const float e = __expf((a[base + (i64)r * KVC] - mu) * rs - M);
        p[base + (i64)r * KVC] = __float2bfloat16(e * inv);
    }
}

// ---------------------------------------------------------------------------
extern "C" void kernel_launch(void* const* d_in, const int* in_sizes, int n_in,
                              void* d_out, int out_size, void* d_ws, size_t ws_size,
                              hipStream_t stream)
{
    (void)in_sizes; (void)n_in; (void)out_size; (void)ws_size;

    const float* emb[4]  = {(const float*)d_in[0], (const float*)d_in[1],
                            (const float*)d_in[2], (const float*)d_in[3]};
    const float* emb_all = (const float*)d_in[4];
    const float* wm[4]   = {(const float*)d_in[5], (const float*)d_in[8],
                            (const float*)d_in[11], (const float*)d_in[14]};
    const float* wq[4]   = {(const float*)d_in[6], (const float*)d_in[9],
                            (const float*)d_in[12], (const float*)d_in[15]};
    const float* wp[4]   = {(const float*)d_in[7], (const float*)d_in[10],
                            (const float*)d_in[13], (const float*)d_in[16]};
    const float* wmk = (const float*)d_in[17];
    const float* wmv = (const float*)d_in[18];
    const float* wk  = (const float*)d_in[19];
    const float* wv  = (const float*)d_in[20];
    float* out = (float*)d_out;

    // ---- workspace regions (timeline-aliased) -----------------------------
    // kb   @0         62,914,560  K (BATCH,960,4096) bf16 — persists
    // vT   @62.9M     62,914,560  V^T (BATCH,4096,960) bf16 — persists
    // Q    @125.8M    62,914,560  embT_all -> vb -> qb_all (BATCH,960,4096)
    // S    @188.7M    67,108,864  sb | {wm-out, embT_i} | {attnT, probsT, probsP}
    // wb   @255.9M     5,079,040  all weights bf16
    // part/stats tail.  total ~261 MB
    char* ws = (char*)d_ws;
    bf16*  kb     = (bf16*)ws;
    bf16*  vT     = (bf16*)(ws + 62914560LL);
    bf16*  Q      = (bf16*)(ws + 125829120LL);
    char*  Sr     = ws + 188743680LL;
    bf16*  sb     = (bf16*)Sr;                   // K/V gemm out; branch wm-out
    bf16*  embT   = (bf16*)(Sr + 33554432LL);    // per-branch transposed emb
    float* attnT  = (float*)Sr;                  // (BATCH,960,960) fp32
    bf16*  probsT = (bf16*)(Sr + 29491200LL);    // (BATCH,960,960) bf16
    bf16*  probsP = (bf16*)(Sr + 44236800LL);    // (BATCH,c,960) bf16
    bf16*  wb     = (bf16*)(ws + 255852544LL);
    float* part   = (float*)(ws + 260931584LL);
    float* stats  = (float*)(ws + 260939776LL);

    const dim3 blk(256);
    const float scale = (float)(1.0 / sqrt((double)KVC));
    const int CNl[4] = {64, 128, 256, 512};
    const int CSl[4] = {0, 64, 192, 448};
    const i64 wmOff[4] = {1843200, 1847296, 1863680, 1929216};
    const i64 wpOff[4] = {2191360, 2195456, 2211840, 2277376};

    // ---- weights -> bf16 --------------------------------------------------
    cvt_weights<<<2480, blk, 0, stream>>>(wmk, wmv, wm[0], wm[1], wm[2], wm[3],
                                          wp[0], wp[1], wp[2], wp[3], wb);

    // ---- emb_all^T (bf16) -> Q -------------------------------------------
    transpose_to_bt<float><<<dim3(64, 15, BATCH), blk, 0, stream>>>(emb_all, Q, KVC);

    // ---- K path: k = l2norm(dw3x3(wmk . emb_all)) ------------------------
    gemm_bt<bf16><<<dim3(32, 8, BATCH), blk, 0, stream>>>(
        wb, KVC, 0, Q, KVC, (i64)HW * KVC, sb, HW, (i64)KVC * HW,
        KVC, HW, KVC, 1.0f);
    dw3x3<<<(BATCH * KVC * HW) / 256, blk, 0, stream>>>(sb, wk, kb, KVC);
    l2norm_rows<<<BATCH * KVC, blk, 0, stream>>>(kb, KVC, 0, KVC);

    // ---- V path: v = dw3x3(wmv . emb_all); vT = v^T ----------------------
    gemm_bt<bf16><<<dim3(32, 8, BATCH), blk, 0, stream>>>(
        wb + 921600, KVC, 0, Q, KVC, (i64)HW * KVC, sb, HW, (i64)KVC * HW,
        KVC, HW, KVC, 1.0f);
    dw3x3<<<(BATCH * KVC * HW) / 256, blk, 0, stream>>>(sb, wv, Q, KVC);  // vb in Q
    transpose_to_bt<bf16><<<dim3(64, 15, BATCH), blk, 0, stream>>>(Q, vT, KVC);

    // ---- all q's into concat buffer qb_all (Q) ---------------------------
    for (int i = 0; i < 4; ++i) {
        const int c = CNl[i], cs = CSl[i];
        transpose_to_bt<float><<<dim3(64, c / 64, BATCH), blk, 0, stream>>>(
            emb[i], embT, c);
        gemm_bt<bf16><<<dim3(32, (c + 127) / 128, BATCH), blk, 0, stream>>>(
            wb + wmOff[i], c, 0, embT, c, (i64)HW * c, sb, HW, (i64)c * HW,
            c, HW, c, 1.0f);
        gconv3x3<<<(BATCH * c * HW) / 256, blk, 0, stream>>>(sb, wq[i], Q, c, KVC, cs);
        l2norm_rows<<<BATCH * c, blk, 0, stream>>>(Q, KVC, cs, c);
    }

    // ---- merged attention scores: attnT = scale * K . Qall^T -------------
    // (M=960 kv, N=960 q-channels, K=4096)
    gemm_bt<float><<<dim3(8, 8, BATCH), blk, 0, stream>>>(
        kb, HW, (i64)KVC * HW, Q, HW, (i64)KVC * HW, attnT, KVC, (i64)KVC * KVC,
        KVC, KVC, HW, scale);

    // ---- per-branch instance-norm stats + column softmax -----------------
    inorm_partial<<<dim3(BATCH, 32, 4), blk, 0, stream>>>(attnT, part);
    inorm_finish<<<dim3(BATCH, 4), 64, 0, stream>>>(part, stats);
    softmax_cols<<<dim3(15, BATCH), blk, 0, stream>>>(attnT, probsT, stats);

    // ---- per branch: probsP = wp . probs ; out = probsP . v --------------
    i64 ooff = 0;
    for (int i = 0; i < 4; ++i) {
        const int c = CNl[i], cs = CSl[i];
        // probsP (c,960) = wp (c,c) . probsT-slice^T   (B=(N=960,K=c))
        gemm_bt<bf16><<<dim3(8, (c + 127) / 128, BATCH), blk, 0, stream>>>(
            wb + wpOff[i], c, 0, probsT + cs, KVC, (i64)KVC * KVC,
            probsP, KVC, (i64)c * KVC, c, KVC, c, 1.0f);
        // out (c,4096) = probsP (c,960) . vT^T         (B=vT (N=4096,K=960))
        gemm_bt<float><<<dim3(32, (c + 127) / 128, BATCH), blk, 0, stream>>>(
            probsP, KVC, (i64)c * KVC, vT, KVC, (i64)HW * KVC,
            out + ooff, HW, (i64)c * HW, c, HW, KVC, 1.0f);
        ooff += (i64)BATCH * c * HW;
    }
}

// Round 2
// 1205.023 us; speedup vs baseline: 2.4186x; 1.4663x over previous
//
#include <hip/hip_runtime.h>
#include <hip/hip_bf16.h>
#include <math.h>

typedef long long i64;
typedef __hip_bfloat16 bf16;

#define HW 4096
#define KVC 960
#define BATCH 8

using bf8 = __attribute__((ext_vector_type(8))) short;   // 8 bf16 (4 VGPRs)
using f32x4 = __attribute__((ext_vector_type(4))) float; // MFMA accum

__device__ __forceinline__ float bf2f(unsigned short u) {
    union { unsigned int i; float f; } c; c.i = ((unsigned int)u) << 16; return c.f;
}
__device__ __forceinline__ float tof(bf16 v) { return __bfloat162float(v); }
__device__ __forceinline__ unsigned short f2bs(float f) {
    bf16 h = __float2bfloat16(f); return *reinterpret_cast<unsigned short*>(&h);
}
__device__ __forceinline__ unsigned short tobs(float f) { return f2bs(f); }
__device__ __forceinline__ unsigned short tobs(bf16 v) { return *reinterpret_cast<unsigned short*>(&v); }
__device__ __forceinline__ void store1(float* p, float v) { *p = v; }
__device__ __forceinline__ void store1(bf16* p, float v) { *p = __float2bfloat16(v); }

// async global->LDS, 16B per lane. LDS dest is wave-uniform base + lane*16.
__device__ __forceinline__ void gl_lds16(const void* g, void* l) {
    __builtin_amdgcn_global_load_lds(
        (const __attribute__((address_space(1))) void*)g,
        (__attribute__((address_space(3))) void*)l,
        16, 0, 0);
}

// ---------------------------------------------------------------------------
// MFMA GEMM, all-bf16 operands: C[bz] = alpha * A[bz] * B[bz]^T
// A: (M,K) bf16 row-major (lda). B: (N,K) bf16 row-major (ldb). C: (M,N)
// fp32/bf16 (ldc). K%32==0. Tile 128x128, BK=32, 4 waves, 4x4
// mfma_f32_16x16x32_bf16 per wave. global_load_lds dwordx4, linear LDS.
// ---------------------------------------------------------------------------
template<typename TC>
__global__ __launch_bounds__(256)
void gemm_bt(const bf16* __restrict__ A, int lda, i64 aBatch,
             const bf16* __restrict__ B, int ldb, i64 bBatch,
             TC* __restrict__ C, int ldc, i64 cBatch,
             int M, int N, int K, float alpha)
{
    __shared__ __align__(16) short As[128 * 32];
    __shared__ __align__(16) short Bs[128 * 32];

    const int bz = blockIdx.z;
    const int m0 = blockIdx.y * 128;
    const int n0 = blockIdx.x * 128;
    const int tid  = threadIdx.x;
    const int lane = tid & 63;
    const int wave = tid >> 6;
    const int wm = (wave & 1) * 64;
    const int wn = (wave >> 1) * 64;
    const int quad = lane >> 4;
    const int l16  = lane & 15;

    const bf16* Ab = A + (i64)bz * aBatch;
    const bf16* Bb = B + (i64)bz * bBatch;

    const int srow = lane >> 2;
    const int scol = (lane & 3) * 8;

    int ar0 = m0 + wave * 16 + srow;       if (ar0 >= M) ar0 = M - 1;
    int ar1 = m0 + 64 + wave * 16 + srow;  if (ar1 >= M) ar1 = M - 1;
    int br0 = n0 + wave * 16 + srow;       if (br0 >= N) br0 = N - 1;
    int br1 = n0 + 64 + wave * 16 + srow;  if (br1 >= N) br1 = N - 1;
    const bf16* pa0 = Ab + (i64)ar0 * lda + scol;
    const bf16* pa1 = Ab + (i64)ar1 * lda + scol;
    const bf16* pb0 = Bb + (i64)br0 * ldb + scol;
    const bf16* pb1 = Bb + (i64)br1 * ldb + scol;

    short* la0 = As + wave * 512;
    short* la1 = As + 2048 + wave * 512;
    short* lb0 = Bs + wave * 512;
    short* lb1 = Bs + 2048 + wave * 512;

    f32x4 acc[4][4] = {};

    for (int k0 = 0; k0 < K; k0 += 32) {
        gl_lds16(pa0 + k0, la0);
        gl_lds16(pa1 + k0, la1);
        gl_lds16(pb0 + k0, lb0);
        gl_lds16(pb1 + k0, lb1);
        __syncthreads();

        bf8 af[4], bfr[4];
        #pragma unroll
        for (int mt = 0; mt < 4; ++mt)
            af[mt] = *(const bf8*)(As + (wm + mt * 16 + l16) * 32 + quad * 8);
        #pragma unroll
        for (int nt = 0; nt < 4; ++nt)
            bfr[nt] = *(const bf8*)(Bs + (wn + nt * 16 + l16) * 32 + quad * 8);
        #pragma unroll
        for (int mt = 0; mt < 4; ++mt)
            #pragma unroll
            for (int nt = 0; nt < 4; ++nt)
                acc[mt][nt] = __builtin_amdgcn_mfma_f32_16x16x32_bf16(
                    af[mt], bfr[nt], acc[mt][nt], 0, 0, 0);
        __syncthreads();
    }

    const i64 cb = (i64)bz * cBatch;
    #pragma unroll
    for (int mt = 0; mt < 4; ++mt) {
        #pragma unroll
        for (int r = 0; r < 4; ++r) {
            const int row = m0 + wm + mt * 16 + quad * 4 + r;
            if (row >= M) continue;
            const i64 rb = cb + (i64)row * ldc;
            #pragma unroll
            for (int nt = 0; nt < 4; ++nt) {
                const int col = n0 + wn + nt * 16 + l16;
                if (col < N) store1(C + rb + col, alpha * acc[mt][nt][r]);
            }
        }
    }
}

// ---------------------------------------------------------------------------
// Tiled transpose + convert: in (BATCH, C, 4096) (fp32 or bf16) ->
// out (BATCH, 4096, C) bf16. C % 64 == 0. 64x64 tiles, pad 66 shorts.
// ---------------------------------------------------------------------------
template<typename T>
__global__ __launch_bounds__(256)
void transpose_to_bt(const T* __restrict__ in, bf16* __restrict__ outT, int C)
{
    __shared__ unsigned short t[64][66];
    const int b  = blockIdx.z;
    const int n0 = blockIdx.x * 64;   // HW dim
    const int c0 = blockIdx.y * 64;   // C dim
    const int tx = threadIdx.x & 63, ty = threadIdx.x >> 6;
    const T* ip = in + ((i64)b * C + c0) * (i64)HW + n0;
    #pragma unroll
    for (int i = 0; i < 16; ++i) {
        const int r = ty + i * 4;
        t[r][tx] = tobs(ip[(i64)r * HW + tx]);
    }
    __syncthreads();
    bf16* op = outT + ((i64)b * HW + n0) * (i64)C + c0;
    #pragma unroll
    for (int i = 0; i < 16; ++i) {
        const int r = ty + i * 4;
        *(unsigned short*)(op + (i64)r * C + tx) = t[tx][r];
    }
}

// ---------------------------------------------------------------------------
// One-shot fp32 -> bf16 conversion of all 10 weight tensors into wb.
// ---------------------------------------------------------------------------
__global__ __launch_bounds__(256)
void cvt_weights(const float* __restrict__ s0, const float* __restrict__ s1,
                 const float* __restrict__ s2, const float* __restrict__ s3,
                 const float* __restrict__ s4, const float* __restrict__ s5,
                 const float* __restrict__ s6, const float* __restrict__ s7,
                 const float* __restrict__ s8, const float* __restrict__ s9,
                 bf16* __restrict__ wb)
{
    const int i = (blockIdx.x * 256 + threadIdx.x) * 4;
    if (i >= 2539520) return;
    const float* src; int off;
    if      (i <  921600) { src = s0; off = 0;       }
    else if (i < 1843200) { src = s1; off = 921600;  }
    else if (i < 1847296) { src = s2; off = 1843200; }
    else if (i < 1863680) { src = s3; off = 1847296; }
    else if (i < 1929216) { src = s4; off = 1863680; }
    else if (i < 2191360) { src = s5; off = 1929216; }
    else if (i < 2195456) { src = s6; off = 2191360; }
    else if (i < 2211840) { src = s7; off = 2195456; }
    else if (i < 2277376) { src = s8; off = 2211840; }
    else                  { src = s9; off = 2277376; }
    const float4 v = *(const float4*)(src + (i - off));
    ushort4 o;
    o.x = f2bs(v.x); o.y = f2bs(v.y); o.z = f2bs(v.z); o.w = f2bs(v.w);
    *(ushort4*)((unsigned short*)wb + i) = o;
}

// ---------------------------------------------------------------------------
// Fused depthwise 3x3 SAME (+ optional per-image-row L2 normalize).
// One block per (b,c) 64x64 image. Image staged to LDS via global_load_lds.
// Thread computes a 4x4 output tile from a 6x6 register halo (LDS read once).
// NORM: block-reduce sum of squares over the 4096 outputs, scale, store.
// ---------------------------------------------------------------------------
template<bool NORM>
__global__ __launch_bounds__(256)
void dw3x3_fused(const bf16* __restrict__ in, const float* __restrict__ w,
                 bf16* __restrict__ out, int C)
{
    __shared__ __align__(16) unsigned short img[4096];
    __shared__ float red[4];
    __shared__ float sinv;
    const int bc = blockIdx.x;
    const int c = bc % C;
    const int tid = threadIdx.x;
    const int lane = tid & 63, wave = tid >> 6;
    const bf16* ip = in + (i64)bc * HW;
    gl_lds16(ip + wave * 512 + lane * 8, img + wave * 512);
    gl_lds16(ip + (4 + wave) * 512 + lane * 8, img + (4 + wave) * 512);

    const float* wp9 = w + c * 9;   // block-uniform -> scalar loads
    float wr[9];
    #pragma unroll
    for (int i = 0; i < 9; ++i) wr[i] = wp9[i];
    __syncthreads();

    const int x0 = (tid & 15) * 4, y0 = (tid >> 4) * 4;
    float fin[6][6];
    #pragma unroll
    for (int r = 0; r < 6; ++r) {
        const int yy = y0 - 1 + r;
        const int yc = (yy < 0) ? 0 : (yy > 63 ? 63 : yy);
        const bool yok = (yy >= 0) && (yy <= 63);
        #pragma unroll
        for (int cc = 0; cc < 6; ++cc) {
            const int xx = x0 - 1 + cc;
            const int xc = (xx < 0) ? 0 : (xx > 63 ? 63 : xx);
            const float v = bf2f(img[yc * 64 + xc]);
            fin[r][cc] = (yok && xx >= 0 && xx <= 63) ? v : 0.f;
        }
    }

    float o[4][4];
    float ss = 0.f;
    #pragma unroll
    for (int r = 0; r < 4; ++r) {
        #pragma unroll
        for (int cc = 0; cc < 4; ++cc) {
            float s = 0.f;
            #pragma unroll
            for (int dy = 0; dy < 3; ++dy)
                #pragma unroll
                for (int dx = 0; dx < 3; ++dx)
                    s = fmaf(wr[dy * 3 + dx], fin[r + dy][cc + dx], s);
            o[r][cc] = s;
            ss = fmaf(s, s, ss);
        }
    }

    float inv = 1.f;
    if (NORM) {
        #pragma unroll
        for (int off = 32; off > 0; off >>= 1) ss += __shfl_down(ss, off);
        const int wid = tid >> 6;
        if (lane == 0) red[wid] = ss;
        __syncthreads();
        if (tid == 0) {
            const float t = red[0] + red[1] + red[2] + red[3];
            sinv = 1.0f / fmaxf(sqrtf(t), 1e-12f);
        }
        __syncthreads();
        inv = sinv;
    }

    bf16* op = out + (i64)bc * HW;
    #pragma unroll
    for (int r = 0; r < 4; ++r) {
        ushort4 pk;
        pk.x = f2bs(o[r][0] * inv);
        pk.y = f2bs(o[r][1] * inv);
        pk.z = f2bs(o[r][2] * inv);
        pk.w = f2bs(o[r][3] * inv);
        *(ushort4*)(op + (y0 + r) * 64 + x0) = pk;
    }
}

// ---------------------------------------------------------------------------
// Fused grouped 3x3 SAME (groups=C/2, 2in/2out) + per-out-channel L2 norm.
// One block per (b, group). Both input images staged to LDS (16 KB);
// computes both output channels, both norms. Writes into (b,960,hw) concat
// buffer at channel offset cstart. w: (C,2,3,3) fp32.
// ---------------------------------------------------------------------------
__global__ __launch_bounds__(256)
void gconv3x3_fused(const bf16* __restrict__ in, const float* __restrict__ w,
                    bf16* __restrict__ outAll, int C, int cstart)
{
    __shared__ __align__(16) unsigned short img[8192];
    __shared__ float red[2][4];
    __shared__ float sinv[2];
    const int nb = C >> 1;
    const int b = blockIdx.x / nb;
    const int g = blockIdx.x % nb;
    const int tid = threadIdx.x, lane = tid & 63, wave = tid >> 6;
    const bf16* ip = in + ((i64)b * C + 2 * g) * HW;   // two contiguous images
    #pragma unroll
    for (int it = 0; it < 4; ++it)
        gl_lds16(ip + (it * 4 + wave) * 512 + lane * 8, img + (it * 4 + wave) * 512);

    const float* wp = w + g * 36;   // block-uniform
    float wr[36];
    #pragma unroll
    for (int i = 0; i < 36; ++i) wr[i] = wp[i];
    __syncthreads();

    const int x0 = (tid & 15) * 4, y0 = (tid >> 4) * 4;
    float fin[2][6][6];
    #pragma unroll
    for (int ic = 0; ic < 2; ++ic) {
        #pragma unroll
        for (int r = 0; r < 6; ++r) {
            const int yy = y0 - 1 + r;
            const int yc = (yy < 0) ? 0 : (yy > 63 ? 63 : yy);
            const bool yok = (yy >= 0) && (yy <= 63);
            #pragma unroll
            for (int cc = 0; cc < 6; ++cc) {
                const int xx = x0 - 1 + cc;
                const int xc = (xx < 0) ? 0 : (xx > 63 ? 63 : xx);
                const float v = bf2f(img[ic * 4096 + yc * 64 + xc]);
                fin[ic][r][cc] = (yok && xx >= 0 && xx <= 63) ? v : 0.f;
            }
        }
    }

    float o[2][4][4];
    float ss0 = 0.f, ss1 = 0.f;
    #pragma unroll
    for (int oc = 0; oc < 2; ++oc) {
        #pragma unroll
        for (int r = 0; r < 4; ++r) {
            #pragma unroll
            for (int cc = 0; cc < 4; ++cc) {
                float s = 0.f;
                #pragma unroll
                for (int ic = 0; ic < 2; ++ic)
                    #pragma unroll
                    for (int dy = 0; dy < 3; ++dy)
                        #pragma unroll
                        for (int dx = 0; dx < 3; ++dx)
                            s = fmaf(wr[oc * 18 + ic * 9 + dy * 3 + dx],
                                     fin[ic][r + dy][cc + dx], s);
                o[oc][r][cc] = s;
                if (oc == 0) ss0 = fmaf(s, s, ss0); else ss1 = fmaf(s, s, ss1);
            }
        }
    }

    #pragma unroll
    for (int off = 32; off > 0; off >>= 1) {
        ss0 += __shfl_down(ss0, off);
        ss1 += __shfl_down(ss1, off);
    }
    const int wid = tid >> 6;
    if (lane == 0) { red[0][wid] = ss0; red[1][wid] = ss1; }
    __syncthreads();
    if (tid == 0) {
        const float t0 = red[0][0] + red[0][1] + red[0][2] + red[0][3];
        const float t1 = red[1][0] + red[1][1] + red[1][2] + red[1][3];
        sinv[0] = 1.0f / fmaxf(sqrtf(t0), 1e-12f);
        sinv[1] = 1.0f / fmaxf(sqrtf(t1), 1e-12f);
    }
    __syncthreads();

    #pragma unroll
    for (int oc = 0; oc < 2; ++oc) {
        const float inv = sinv[oc];
        bf16* op = outAll + ((i64)b * KVC + cstart + 2 * g + oc) * HW;
        #pragma unroll
        for (int r = 0; r < 4; ++r) {
            ushort4 pk;
            pk.x = f2bs(o[oc][r][0] * inv);
            pk.y = f2bs(o[oc][r][1] * inv);
            pk.z = f2bs(o[oc][r][2] * inv);
            pk.w = f2bs(o[oc][r][3] * inv);
            *(ushort4*)(op + (y0 + r) * 64 + x0) = pk;
        }
    }
}

// ---------------------------------------------------------------------------
// Instance-norm stats over branch slice of attnT (BATCH, 960, 960) fp32.
// ---------------------------------------------------------------------------
__global__ __launch_bounds__(256)
void inorm_partial(const float* __restrict__ a, float* __restrict__ part)
{
    const int b = blockIdx.x, ch = blockIdx.y, br = blockIdx.z;
    const int CC[4] = {64, 128, 256, 512};
    const int CS[4] = {0, 64, 192, 448};
    const int c = CC[br], cs = CS[br];
    const int csh = 31 - __clz(c);
    const int cmask = c - 1;
    const float* p = a + (i64)b * (KVC * KVC) + (i64)(ch * 30) * KVC + cs;
    const int tot = 30 * c;
    float s = 0.f, s2 = 0.f;
    for (int i = threadIdx.x; i < tot; i += 256) {
        const float v = p[(i64)(i >> csh) * KVC + (i & cmask)];
        s += v;
        s2 = fmaf(v, v, s2);
    }
    #pragma unroll
    for (int o = 32; o > 0; o >>= 1) { s += __shfl_down(s, o); s2 += __shfl_down(s2, o); }
    __shared__ float r1[4], r2[4];
    const int lane = threadIdx.x & 63, wid = threadIdx.x >> 6;
    if (lane == 0) { r1[wid] = s; r2[wid] = s2; }
    __syncthreads();
    if (threadIdx.x == 0) {
        part[((br * 8 + b) * 32 + ch) * 2 + 0] = r1[0] + r1[1] + r1[2] + r1[3];
        part[((br * 8 + b) * 32 + ch) * 2 + 1] = r2[0] + r2[1] + r2[2] + r2[3];
    }
}

__global__ __launch_bounds__(64)
void inorm_finish(const float* __restrict__ part, float* __restrict__ stats)
{
    const int b = blockIdx.x, br = blockIdx.y;
    const int i = threadIdx.x;
    float s = 0.f, s2 = 0.f;
    if (i < 32) {
        s  = part[((br * 8 + b) * 32 + i) * 2 + 0];
        s2 = part[((br * 8 + b) * 32 + i) * 2 + 1];
    }
    #pragma unroll
    for (int o = 16; o > 0; o >>= 1) { s += __shfl_down(s, o); s2 += __shfl_down(s2, o); }
    if (i == 0) {
        const int CC[4] = {64, 128, 256, 512};
        const float n = (float)(CC[br] * KVC);
        const float mu = s / n;
        const float var = s2 / n - mu * mu;
        stats[(br * 8 + b) * 2 + 0] = mu;
        stats[(br * 8 + b) * 2 + 1] = rsqrtf(var + 1e-5f);
    }
}

// ---------------------------------------------------------------------------
// Column softmax over attnT (BATCH, 960 kv-rows, 960 q-cols) with per-branch
// instance-norm transform; writes probsT bf16 (same layout).
// ---------------------------------------------------------------------------
__global__ __launch_bounds__(256)
void softmax_cols(const float* __restrict__ a, bf16* __restrict__ p,
                  const float* __restrict__ stats)
{
    const int b  = blockIdx.y;
    const int cb = blockIdx.x * 64;
    const int br = (cb >= 448) ? 3 : (cb >= 192) ? 2 : (cb >= 64) ? 1 : 0;
    const int tx = threadIdx.x & 63, ty = threadIdx.x >> 6;
    const float mu = stats[(br * 8 + b) * 2 + 0];
    const float rs = stats[(br * 8 + b) * 2 + 1];
    const i64 base = (i64)b * (KVC * KVC) + cb + tx;

    float mx = -1e30f;
    for (int r = ty; r < KVC; r += 4)
        mx = fmaxf(mx, a[base + (i64)r * KVC]);
    __shared__ float red[4][64];
    red[ty][tx] = mx;
    __syncthreads();
    mx = fmaxf(fmaxf(red[0][tx], red[1][tx]), fmaxf(red[2][tx], red[3][tx]));
    const float M = (mx - mu) * rs;   // rs > 0: transform is monotone

    float se = 0.f;
    for (int r = ty; r < KVC; r += 4)
        se += __expf((a[base + (i64)r * KVC] - mu) * rs - M);
    __syncthreads();
    red[ty][tx] = se;
    __syncthreads();
    const float S = red[0][tx] + red[1][tx] + red[2][tx] + red[3][tx];
    const float inv = 1.0f / S;

    for (int r = ty; r < KVC; r += 4) {
        const float e = __expf((a[base + (i64)r * KVC] - mu) * rs - M);
        p[base + (i64)r * KVC] = __float2bfloat16(e * inv);
    }
}

// ---------------------------------------------------------------------------
extern "C" void kernel_launch(void* const* d_in, const int* in_sizes, int n_in,
                              void* d_out, int out_size, void* d_ws, size_t ws_size,
                              hipStream_t stream)
{
    (void)in_sizes; (void)n_in; (void)out_size; (void)ws_size;

    const float* emb[4]  = {(const float*)d_in[0], (const float*)d_in[1],
                            (const float*)d_in[2], (const float*)d_in[3]};
    const float* emb_all = (const float*)d_in[4];
    const float* wq[4]   = {(const float*)d_in[6], (const float*)d_in[9],
                            (const float*)d_in[12], (const float*)d_in[15]};
    const float* wmk = (const float*)d_in[17];
    const float* wmv = (const float*)d_in[18];
    const float* wk  = (const float*)d_in[19];
    const float* wv  = (const float*)d_in[20];
    float* out = (float*)d_out;

    // ---- workspace regions (timeline-aliased, same as round 1) -----------
    char* ws = (char*)d_ws;
    bf16*  kb     = (bf16*)ws;                   // K (B,960,4096) bf16
    bf16*  vT     = (bf16*)(ws + 62914560LL);    // V^T (B,4096,960) bf16
    bf16*  Q      = (bf16*)(ws + 125829120LL);   // embT_all -> vb -> q concat
    char*  Sr     = ws + 188743680LL;
    bf16*  sb     = (bf16*)Sr;                   // pre-conv GEMM out
    bf16*  embT   = (bf16*)(Sr + 33554432LL);    // per-branch transposed emb
    float* attnT  = (float*)Sr;                  // (B,960,960) fp32
    bf16*  probsT = (bf16*)(Sr + 29491200LL);    // (B,960,960) bf16
    bf16*  probsP = (bf16*)(Sr + 44236800LL);    // (B,c,960) bf16
    bf16*  wb     = (bf16*)(ws + 255852544LL);
    float* part   = (float*)(ws + 260931584LL);
    float* stats  = (float*)(ws + 260939776LL);

    const dim3 blk(256);
    const float scale = (float)(1.0 / sqrt((double)KVC));
    const int CNl[4] = {64, 128, 256, 512};
    const int CSl[4] = {0, 64, 192, 448};
    const i64 wmOff[4] = {1843200, 1847296, 1863680, 1929216};
    const i64 wpOff[4] = {2191360, 2195456, 2211840, 2277376};

    // ---- weights -> bf16 --------------------------------------------------
    cvt_weights<<<2480, blk, 0, stream>>>(wmk, wmv,
        (const float*)d_in[5], (const float*)d_in[8],
        (const float*)d_in[11], (const float*)d_in[14],
        (const float*)d_in[7], (const float*)d_in[10],
        (const float*)d_in[13], (const float*)d_in[16], wb);

    // ---- emb_all^T (bf16) -> Q -------------------------------------------
    transpose_to_bt<float><<<dim3(64, 15, BATCH), blk, 0, stream>>>(emb_all, Q, KVC);

    // ---- K path: k = l2norm(dw3x3(wmk . emb_all)) (conv+norm fused) ------
    gemm_bt<bf16><<<dim3(32, 8, BATCH), blk, 0, stream>>>(
        wb, KVC, 0, Q, KVC, (i64)HW * KVC, sb, HW, (i64)KVC * HW,
        KVC, HW, KVC, 1.0f);
    dw3x3_fused<true><<<BATCH * KVC, blk, 0, stream>>>(sb, wk, kb, KVC);

    // ---- V path: v = dw3x3(wmv . emb_all); vT = v^T ----------------------
    gemm_bt<bf16><<<dim3(32, 8, BATCH), blk, 0, stream>>>(
        wb + 921600, KVC, 0, Q, KVC, (i64)HW * KVC, sb, HW, (i64)KVC * HW,
        KVC, HW, KVC, 1.0f);
    dw3x3_fused<false><<<BATCH * KVC, blk, 0, stream>>>(sb, wv, Q, KVC); // vb in Q
    transpose_to_bt<bf16><<<dim3(64, 15, BATCH), blk, 0, stream>>>(Q, vT, KVC);

    // ---- all q's into concat buffer (Q); gconv+l2norm fused --------------
    for (int i = 0; i < 4; ++i) {
        const int c = CNl[i], cs = CSl[i];
        transpose_to_bt<float><<<dim3(64, c / 64, BATCH), blk, 0, stream>>>(
            emb[i], embT, c);
        gemm_bt<bf16><<<dim3(32, (c + 127) / 128, BATCH), blk, 0, stream>>>(
            wb + wmOff[i], c, 0, embT, c, (i64)HW * c, sb, HW, (i64)c * HW,
            c, HW, c, 1.0f);
        gconv3x3_fused<<<BATCH * (c / 2), blk, 0, stream>>>(sb, wq[i], Q, c, cs);
    }

    // ---- merged attention scores: attnT = scale * K . Qall^T -------------
    gemm_bt<float><<<dim3(8, 8, BATCH), blk, 0, stream>>>(
        kb, HW, (i64)KVC * HW, Q, HW, (i64)KVC * HW, attnT, KVC, (i64)KVC * KVC,
        KVC, KVC, HW, scale);

    // ---- per-branch instance-norm stats + column softmax -----------------
    inorm_partial<<<dim3(BATCH, 32, 4), blk, 0, stream>>>(attnT, part);
    inorm_finish<<<dim3(BATCH, 4), 64, 0, stream>>>(part, stats);
    softmax_cols<<<dim3(15, BATCH), blk, 0, stream>>>(attnT, probsT, stats);

    // ---- per branch: probsP = wp . probs ; out = probsP . v --------------
    i64 ooff = 0;
    for (int i = 0; i < 4; ++i) {
        const int c = CNl[i], cs = CSl[i];
        gemm_bt<bf16><<<dim3(8, (c + 127) / 128, BATCH), blk, 0, stream>>>(
            wb + wpOff[i], c, 0, probsT + cs, KVC, (i64)KVC * KVC,
            probsP, KVC, (i64)c * KVC, c, KVC, c, 1.0f);
        gemm_bt<float><<<dim3(32, (c + 127) / 128, BATCH), blk, 0, stream>>>(
            probsP, KVC, (i64)c * KVC, vT, KVC, (i64)HW * KVC,
            out + ooff, HW, (i64)c * HW, c, HW, KVC, 1.0f);
        ooff += (i64)BATCH * c * HW;
    }
}

// Round 3
// 1042.055 us; speedup vs baseline: 2.7968x; 1.1564x over previous
//
#include <hip/hip_runtime.h>
#include <hip/hip_bf16.h>
#include <math.h>

typedef long long i64;
typedef __hip_bfloat16 bf16;

#define HW 4096
#define KVC 960
#define BATCH 8

using bf8 = __attribute__((ext_vector_type(8))) short;   // 8 bf16 (4 VGPRs)
using f32x4 = __attribute__((ext_vector_type(4))) float; // MFMA accum

__device__ __forceinline__ float bf2f(unsigned short u) {
    union { unsigned int i; float f; } c; c.i = ((unsigned int)u) << 16; return c.f;
}
__device__ __forceinline__ float tof(bf16 v) { return __bfloat162float(v); }
__device__ __forceinline__ unsigned short f2bs(float f) {
    bf16 h = __float2bfloat16(f); return *reinterpret_cast<unsigned short*>(&h);
}
__device__ __forceinline__ unsigned short tobs(float f) { return f2bs(f); }
__device__ __forceinline__ unsigned short tobs(bf16 v) { return *reinterpret_cast<unsigned short*>(&v); }
__device__ __forceinline__ void store1(float* p, float v) { *p = v; }
__device__ __forceinline__ void store1(bf16* p, float v) { *p = __float2bfloat16(v); }

// async global->LDS, 16B per lane. LDS dest is wave-uniform base + lane*16.
__device__ __forceinline__ void gl_lds16(const void* g, void* l) {
    __builtin_amdgcn_global_load_lds(
        (const __attribute__((address_space(1))) void*)g,
        (__attribute__((address_space(3))) void*)l,
        16, 0, 0);
}

// ---------------------------------------------------------------------------
// MFMA GEMM, all-bf16 operands: C[bz] = alpha * A[bz] * B[bz]^T
// A: (M,K) bf16 row-major (lda). B: (N,K) bf16 row-major (ldb). C: (M,N)
// fp32/bf16 (ldc). K%32==0. Tile 128x128, BK=32, 4 waves, 4x4
// mfma_f32_16x16x32_bf16 per wave. global_load_lds dwordx4, linear LDS.
// ---------------------------------------------------------------------------
template<typename TC>
__global__ __launch_bounds__(256)
void gemm_bt(const bf16* __restrict__ A, int lda, i64 aBatch,
             const bf16* __restrict__ B, int ldb, i64 bBatch,
             TC* __restrict__ C, int ldc, i64 cBatch,
             int M, int N, int K, float alpha)
{
    __shared__ __align__(16) short As[128 * 32];
    __shared__ __align__(16) short Bs[128 * 32];

    const int bz = blockIdx.z;
    const int m0 = blockIdx.y * 128;
    const int n0 = blockIdx.x * 128;
    const int tid  = threadIdx.x;
    const int lane = tid & 63;
    const int wave = tid >> 6;
    const int wm = (wave & 1) * 64;
    const int wn = (wave >> 1) * 64;
    const int quad = lane >> 4;
    const int l16  = lane & 15;

    const bf16* Ab = A + (i64)bz * aBatch;
    const bf16* Bb = B + (i64)bz * bBatch;

    const int srow = lane >> 2;
    const int scol = (lane & 3) * 8;

    int ar0 = m0 + wave * 16 + srow;       if (ar0 >= M) ar0 = M - 1;
    int ar1 = m0 + 64 + wave * 16 + srow;  if (ar1 >= M) ar1 = M - 1;
    int br0 = n0 + wave * 16 + srow;       if (br0 >= N) br0 = N - 1;
    int br1 = n0 + 64 + wave * 16 + srow;  if (br1 >= N) br1 = N - 1;
    const bf16* pa0 = Ab + (i64)ar0 * lda + scol;
    const bf16* pa1 = Ab + (i64)ar1 * lda + scol;
    const bf16* pb0 = Bb + (i64)br0 * ldb + scol;
    const bf16* pb1 = Bb + (i64)br1 * ldb + scol;

    short* la0 = As + wave * 512;
    short* la1 = As + 2048 + wave * 512;
    short* lb0 = Bs + wave * 512;
    short* lb1 = Bs + 2048 + wave * 512;

    f32x4 acc[4][4] = {};

    for (int k0 = 0; k0 < K; k0 += 32) {
        gl_lds16(pa0 + k0, la0);
        gl_lds16(pa1 + k0, la1);
        gl_lds16(pb0 + k0, lb0);
        gl_lds16(pb1 + k0, lb1);
        __syncthreads();

        bf8 af[4], bfr[4];
        #pragma unroll
        for (int mt = 0; mt < 4; ++mt)
            af[mt] = *(const bf8*)(As + (wm + mt * 16 + l16) * 32 + quad * 8);
        #pragma unroll
        for (int nt = 0; nt < 4; ++nt)
            bfr[nt] = *(const bf8*)(Bs + (wn + nt * 16 + l16) * 32 + quad * 8);
        #pragma unroll
        for (int mt = 0; mt < 4; ++mt)
            #pragma unroll
            for (int nt = 0; nt < 4; ++nt)
                acc[mt][nt] = __builtin_amdgcn_mfma_f32_16x16x32_bf16(
                    af[mt], bfr[nt], acc[mt][nt], 0, 0, 0);
        __syncthreads();
    }

    const i64 cb = (i64)bz * cBatch;
    #pragma unroll
    for (int mt = 0; mt < 4; ++mt) {
        #pragma unroll
        for (int r = 0; r < 4; ++r) {
            const int row = m0 + wm + mt * 16 + quad * 4 + r;
            if (row >= M) continue;
            const i64 rb = cb + (i64)row * ldc;
            #pragma unroll
            for (int nt = 0; nt < 4; ++nt) {
                const int col = n0 + wn + nt * 16 + l16;
                if (col < N) store1(C + rb + col, alpha * acc[mt][nt][r]);
            }
        }
    }
}

// ---------------------------------------------------------------------------
// Tiled transpose + convert: in (BATCH, C, 4096) (fp32 or bf16) ->
// out (BATCH, 4096, C) bf16. C % 64 == 0. 64x64 tiles, pad 66 shorts.
// ---------------------------------------------------------------------------
template<typename T>
__global__ __launch_bounds__(256)
void transpose_to_bt(const T* __restrict__ in, bf16* __restrict__ outT, int C)
{
    __shared__ unsigned short t[64][66];
    const int b  = blockIdx.z;
    const int n0 = blockIdx.x * 64;   // HW dim
    const int c0 = blockIdx.y * 64;   // C dim
    const int tx = threadIdx.x & 63, ty = threadIdx.x >> 6;
    const T* ip = in + ((i64)b * C + c0) * (i64)HW + n0;
    #pragma unroll
    for (int i = 0; i < 16; ++i) {
        const int r = ty + i * 4;
        t[r][tx] = tobs(ip[(i64)r * HW + tx]);
    }
    __syncthreads();
    bf16* op = outT + ((i64)b * HW + n0) * (i64)C + c0;
    #pragma unroll
    for (int i = 0; i < 16; ++i) {
        const int r = ty + i * 4;
        *(unsigned short*)(op + (i64)r * C + tx) = t[tx][r];
    }
}

// ---------------------------------------------------------------------------
// Square bf16 transpose: in (BATCH, 960, 960) -> out (BATCH, 960, 960)^T.
// 64x64 tiles, grid (15, 15, BATCH).
// ---------------------------------------------------------------------------
__global__ __launch_bounds__(256)
void transpose_sq(const bf16* __restrict__ in, bf16* __restrict__ out)
{
    __shared__ unsigned short t[64][66];
    const int b  = blockIdx.z;
    const int r0 = blockIdx.y * 64;
    const int c0 = blockIdx.x * 64;
    const int tx = threadIdx.x & 63, ty = threadIdx.x >> 6;
    const bf16* ip = in + ((i64)b * KVC + r0) * KVC + c0;
    #pragma unroll
    for (int i = 0; i < 16; ++i) {
        const int r = ty + i * 4;
        t[r][tx] = tobs(ip[(i64)r * KVC + tx]);
    }
    __syncthreads();
    bf16* op = out + ((i64)b * KVC + c0) * KVC + r0;
    #pragma unroll
    for (int i = 0; i < 16; ++i) {
        const int r = ty + i * 4;
        *(unsigned short*)(op + (i64)r * KVC + tx) = t[tx][r];
    }
}

// ---------------------------------------------------------------------------
// One-shot fp32 -> bf16 conversion of all 10 weight tensors into wb.
// ---------------------------------------------------------------------------
__global__ __launch_bounds__(256)
void cvt_weights(const float* __restrict__ s0, const float* __restrict__ s1,
                 const float* __restrict__ s2, const float* __restrict__ s3,
                 const float* __restrict__ s4, const float* __restrict__ s5,
                 const float* __restrict__ s6, const float* __restrict__ s7,
                 const float* __restrict__ s8, const float* __restrict__ s9,
                 bf16* __restrict__ wb)
{
    const int i = (blockIdx.x * 256 + threadIdx.x) * 4;
    if (i >= 2539520) return;
    const float* src; int off;
    if      (i <  921600) { src = s0; off = 0;       }
    else if (i < 1843200) { src = s1; off = 921600;  }
    else if (i < 1847296) { src = s2; off = 1843200; }
    else if (i < 1863680) { src = s3; off = 1847296; }
    else if (i < 1929216) { src = s4; off = 1863680; }
    else if (i < 2191360) { src = s5; off = 1929216; }
    else if (i < 2195456) { src = s6; off = 2191360; }
    else if (i < 2211840) { src = s7; off = 2195456; }
    else if (i < 2277376) { src = s8; off = 2211840; }
    else                  { src = s9; off = 2277376; }
    const float4 v = *(const float4*)(src + (i - off));
    ushort4 o;
    o.x = f2bs(v.x); o.y = f2bs(v.y); o.z = f2bs(v.z); o.w = f2bs(v.w);
    *(ushort4*)((unsigned short*)wb + i) = o;
}

// ---------------------------------------------------------------------------
// Fused depthwise 3x3 SAME (+ optional per-image L2 normalize).
// One block per (b,c) 64x64 image, staged via global_load_lds; 4x4 reg tile.
// ---------------------------------------------------------------------------
template<bool NORM>
__global__ __launch_bounds__(256)
void dw3x3_fused(const bf16* __restrict__ in, const float* __restrict__ w,
                 bf16* __restrict__ out, int C)
{
    __shared__ __align__(16) unsigned short img[4096];
    __shared__ float red[4];
    __shared__ float sinv;
    const int bc = blockIdx.x;
    const int c = bc % C;
    const int tid = threadIdx.x;
    const int lane = tid & 63, wave = tid >> 6;
    const bf16* ip = in + (i64)bc * HW;
    gl_lds16(ip + wave * 512 + lane * 8, img + wave * 512);
    gl_lds16(ip + (4 + wave) * 512 + lane * 8, img + (4 + wave) * 512);

    const float* wp9 = w + c * 9;
    float wr[9];
    #pragma unroll
    for (int i = 0; i < 9; ++i) wr[i] = wp9[i];
    __syncthreads();

    const int x0 = (tid & 15) * 4, y0 = (tid >> 4) * 4;
    float fin[6][6];
    #pragma unroll
    for (int r = 0; r < 6; ++r) {
        const int yy = y0 - 1 + r;
        const int yc = (yy < 0) ? 0 : (yy > 63 ? 63 : yy);
        const bool yok = (yy >= 0) && (yy <= 63);
        #pragma unroll
        for (int cc = 0; cc < 6; ++cc) {
            const int xx = x0 - 1 + cc;
            const int xc = (xx < 0) ? 0 : (xx > 63 ? 63 : xx);
            const float v = bf2f(img[yc * 64 + xc]);
            fin[r][cc] = (yok && xx >= 0 && xx <= 63) ? v : 0.f;
        }
    }

    float o[4][4];
    float ss = 0.f;
    #pragma unroll
    for (int r = 0; r < 4; ++r) {
        #pragma unroll
        for (int cc = 0; cc < 4; ++cc) {
            float s = 0.f;
            #pragma unroll
            for (int dy = 0; dy < 3; ++dy)
                #pragma unroll
                for (int dx = 0; dx < 3; ++dx)
                    s = fmaf(wr[dy * 3 + dx], fin[r + dy][cc + dx], s);
            o[r][cc] = s;
            ss = fmaf(s, s, ss);
        }
    }

    float inv = 1.f;
    if (NORM) {
        #pragma unroll
        for (int off = 32; off > 0; off >>= 1) ss += __shfl_down(ss, off);
        const int wid = tid >> 6;
        if (lane == 0) red[wid] = ss;
        __syncthreads();
        if (tid == 0) {
            const float t = red[0] + red[1] + red[2] + red[3];
            sinv = 1.0f / fmaxf(sqrtf(t), 1e-12f);
        }
        __syncthreads();
        inv = sinv;
    }

    bf16* op = out + (i64)bc * HW;
    #pragma unroll
    for (int r = 0; r < 4; ++r) {
        ushort4 pk;
        pk.x = f2bs(o[r][0] * inv);
        pk.y = f2bs(o[r][1] * inv);
        pk.z = f2bs(o[r][2] * inv);
        pk.w = f2bs(o[r][3] * inv);
        *(ushort4*)(op + (y0 + r) * 64 + x0) = pk;
    }
}

// ---------------------------------------------------------------------------
// Fused grouped 3x3 SAME (groups=C/2, 2in/2out) + per-out-channel L2 norm.
// One block per (b, group); writes (b,960,hw) concat buffer at cstart.
// ---------------------------------------------------------------------------
__global__ __launch_bounds__(256)
void gconv3x3_fused(const bf16* __restrict__ in, const float* __restrict__ w,
                    bf16* __restrict__ outAll, int C, int cstart)
{
    __shared__ __align__(16) unsigned short img[8192];
    __shared__ float red[2][4];
    __shared__ float sinv[2];
    const int nb = C >> 1;
    const int b = blockIdx.x / nb;
    const int g = blockIdx.x % nb;
    const int tid = threadIdx.x, lane = tid & 63, wave = tid >> 6;
    const bf16* ip = in + ((i64)b * C + 2 * g) * HW;
    #pragma unroll
    for (int it = 0; it < 4; ++it)
        gl_lds16(ip + (it * 4 + wave) * 512 + lane * 8, img + (it * 4 + wave) * 512);

    const float* wp = w + g * 36;
    float wr[36];
    #pragma unroll
    for (int i = 0; i < 36; ++i) wr[i] = wp[i];
    __syncthreads();

    const int x0 = (tid & 15) * 4, y0 = (tid >> 4) * 4;
    float fin[2][6][6];
    #pragma unroll
    for (int ic = 0; ic < 2; ++ic) {
        #pragma unroll
        for (int r = 0; r < 6; ++r) {
            const int yy = y0 - 1 + r;
            const int yc = (yy < 0) ? 0 : (yy > 63 ? 63 : yy);
            const bool yok = (yy >= 0) && (yy <= 63);
            #pragma unroll
            for (int cc = 0; cc < 6; ++cc) {
                const int xx = x0 - 1 + cc;
                const int xc = (xx < 0) ? 0 : (xx > 63 ? 63 : xx);
                const float v = bf2f(img[ic * 4096 + yc * 64 + xc]);
                fin[ic][r][cc] = (yok && xx >= 0 && xx <= 63) ? v : 0.f;
            }
        }
    }

    float o[2][4][4];
    float ss0 = 0.f, ss1 = 0.f;
    #pragma unroll
    for (int oc = 0; oc < 2; ++oc) {
        #pragma unroll
        for (int r = 0; r < 4; ++r) {
            #pragma unroll
            for (int cc = 0; cc < 4; ++cc) {
                float s = 0.f;
                #pragma unroll
                for (int ic = 0; ic < 2; ++ic)
                    #pragma unroll
                    for (int dy = 0; dy < 3; ++dy)
                        #pragma unroll
                        for (int dx = 0; dx < 3; ++dx)
                            s = fmaf(wr[oc * 18 + ic * 9 + dy * 3 + dx],
                                     fin[ic][r + dy][cc + dx], s);
                o[oc][r][cc] = s;
                if (oc == 0) ss0 = fmaf(s, s, ss0); else ss1 = fmaf(s, s, ss1);
            }
        }
    }

    #pragma unroll
    for (int off = 32; off > 0; off >>= 1) {
        ss0 += __shfl_down(ss0, off);
        ss1 += __shfl_down(ss1, off);
    }
    const int wid = tid >> 6;
    if (lane == 0) { red[0][wid] = ss0; red[1][wid] = ss1; }
    __syncthreads();
    if (tid == 0) {
        const float t0 = red[0][0] + red[0][1] + red[0][2] + red[0][3];
        const float t1 = red[1][0] + red[1][1] + red[1][2] + red[1][3];
        sinv[0] = 1.0f / fmaxf(sqrtf(t0), 1e-12f);
        sinv[1] = 1.0f / fmaxf(sqrtf(t1), 1e-12f);
    }
    __syncthreads();

    #pragma unroll
    for (int oc = 0; oc < 2; ++oc) {
        const float inv = sinv[oc];
        bf16* op = outAll + ((i64)b * KVC + cstart + 2 * g + oc) * HW;
        #pragma unroll
        for (int r = 0; r < 4; ++r) {
            ushort4 pk;
            pk.x = f2bs(o[oc][r][0] * inv);
            pk.y = f2bs(o[oc][r][1] * inv);
            pk.z = f2bs(o[oc][r][2] * inv);
            pk.w = f2bs(o[oc][r][3] * inv);
            *(ushort4*)(op + (y0 + r) * 64 + x0) = pk;
        }
    }
}

// ---------------------------------------------------------------------------
// Instance-norm stats over attn (BATCH, 960 q-rows, 960 kv-cols) fp32.
// Branch br = q-rows [CS,CS+c): one CONTIGUOUS c*960-float range per (b,br).
// Grid (BATCH, 32, 4); float4 loads.
// ---------------------------------------------------------------------------
__global__ __launch_bounds__(256)
void inorm_partial(const float* __restrict__ a, float* __restrict__ part)
{
    const int b = blockIdx.x, ch = blockIdx.y, br = blockIdx.z;
    const int CC[4] = {64, 128, 256, 512};
    const int CS[4] = {0, 64, 192, 448};
    const int c = CC[br];
    const int n4 = c * 30 / 4;          // float4s per chunk (c*960/32/4)
    const float4* p = (const float4*)(a + (i64)b * (KVC * KVC)
                                        + (i64)CS[br] * KVC) + (i64)ch * n4;
    float s = 0.f, s2 = 0.f;
    for (int i = threadIdx.x; i < n4; i += 256) {
        const float4 v = p[i];
        s += v.x + v.y + v.z + v.w;
        s2 += v.x * v.x + v.y * v.y + v.z * v.z + v.w * v.w;
    }
    #pragma unroll
    for (int o = 32; o > 0; o >>= 1) { s += __shfl_down(s, o); s2 += __shfl_down(s2, o); }
    __shared__ float r1[4], r2[4];
    const int lane = threadIdx.x & 63, wid = threadIdx.x >> 6;
    if (lane == 0) { r1[wid] = s; r2[wid] = s2; }
    __syncthreads();
    if (threadIdx.x == 0) {
        part[((br * 8 + b) * 32 + ch) * 2 + 0] = r1[0] + r1[1] + r1[2] + r1[3];
        part[((br * 8 + b) * 32 + ch) * 2 + 1] = r2[0] + r2[1] + r2[2] + r2[3];
    }
}

__global__ __launch_bounds__(64)
void inorm_finish(const float* __restrict__ part, float* __restrict__ stats)
{
    const int b = blockIdx.x, br = blockIdx.y;
    const int i = threadIdx.x;
    float s = 0.f, s2 = 0.f;
    if (i < 32) {
        s  = part[((br * 8 + b) * 32 + i) * 2 + 0];
        s2 = part[((br * 8 + b) * 32 + i) * 2 + 1];
    }
    #pragma unroll
    for (int o = 16; o > 0; o >>= 1) { s += __shfl_down(s, o); s2 += __shfl_down(s2, o); }
    if (i == 0) {
        const int CC[4] = {64, 128, 256, 512};
        const float n = (float)(CC[br] * KVC);
        const float mu = s / n;
        const float var = s2 / n - mu * mu;
        stats[(br * 8 + b) * 2 + 0] = mu;
        stats[(br * 8 + b) * 2 + 1] = rsqrtf(var + 1e-5f);
    }
}

// ---------------------------------------------------------------------------
// Row softmax over attn (BATCH, 960 q-rows, 960 kv-cols contiguous) with
// per-branch instance-norm transform; writes probs bf16 same layout.
// One block per (b,q) row; row cached in registers (float4, 240 lanes).
// ---------------------------------------------------------------------------
__global__ __launch_bounds__(256)
void softmax_rows(const float* __restrict__ a, bf16* __restrict__ p,
                  const float* __restrict__ stats)
{
    const int q = blockIdx.x, b = blockIdx.y;
    const int br = (q >= 448) ? 3 : (q >= 192) ? 2 : (q >= 64) ? 1 : 0;
    const float mu = stats[(br * 8 + b) * 2 + 0];
    const float rs = stats[(br * 8 + b) * 2 + 1];
    const i64 base = ((i64)b * KVC + q) * KVC;
    const int t = threadIdx.x;
    const bool act = t < 240;

    float x[4];
    float mx = -1e30f;
    if (act) {
        const float4 v = ((const float4*)(a + base))[t];
        x[0] = (v.x - mu) * rs; x[1] = (v.y - mu) * rs;
        x[2] = (v.z - mu) * rs; x[3] = (v.w - mu) * rs;
        mx = fmaxf(fmaxf(x[0], x[1]), fmaxf(x[2], x[3]));
    }
    __shared__ float red[4];
    __shared__ float bM, bS;
    const int lane = t & 63, wid = t >> 6;
    #pragma unroll
    for (int o = 32; o > 0; o >>= 1) mx = fmaxf(mx, __shfl_down(mx, o));
    if (lane == 0) red[wid] = mx;
    __syncthreads();
    if (t == 0) bM = fmaxf(fmaxf(red[0], red[1]), fmaxf(red[2], red[3]));
    __syncthreads();
    const float M = bM;

    float e[4];
    float se = 0.f;
    if (act) {
        #pragma unroll
        for (int j = 0; j < 4; ++j) { e[j] = __expf(x[j] - M); se += e[j]; }
    }
    #pragma unroll
    for (int o = 32; o > 0; o >>= 1) se += __shfl_down(se, o);
    if (lane == 0) red[wid] = se;
    __syncthreads();
    if (t == 0) bS = red[0] + red[1] + red[2] + red[3];
    __syncthreads();
    const float inv = 1.0f / bS;

    if (act) {
        ushort4 o4;
        o4.x = f2bs(e[0] * inv); o4.y = f2bs(e[1] * inv);
        o4.z = f2bs(e[2] * inv); o4.w = f2bs(e[3] * inv);
        ((ushort4*)((unsigned short*)p + base))[t] = o4;
    }
}

// ---------------------------------------------------------------------------
extern "C" void kernel_launch(void* const* d_in, const int* in_sizes, int n_in,
                              void* d_out, int out_size, void* d_ws, size_t ws_size,
                              hipStream_t stream)
{
    (void)in_sizes; (void)n_in; (void)out_size; (void)ws_size;

    const float* emb[4]  = {(const float*)d_in[0], (const float*)d_in[1],
                            (const float*)d_in[2], (const float*)d_in[3]};
    const float* emb_all = (const float*)d_in[4];
    const float* wq[4]   = {(const float*)d_in[6], (const float*)d_in[9],
                            (const float*)d_in[12], (const float*)d_in[15]};
    const float* wmk = (const float*)d_in[17];
    const float* wmv = (const float*)d_in[18];
    const float* wk  = (const float*)d_in[19];
    const float* wv  = (const float*)d_in[20];
    float* out = (float*)d_out;

    // ---- workspace regions (timeline-aliased) ----------------------------
    // kb @0 (62.9M) | vT @62.9M (62.9M) | Q @125.8M (62.9M)
    // Sr @188.7M (67.1M): sb | embT@+33.55M | attn@0, probsT@+29.49M,
    //                     probsP@+44.24M, pbuf@+52.10M
    // wb @255.85M | part/stats tail
    char* ws = (char*)d_ws;
    bf16*  kb     = (bf16*)ws;
    bf16*  vT     = (bf16*)(ws + 62914560LL);
    bf16*  Q      = (bf16*)(ws + 125829120LL);
    char*  Sr     = ws + 188743680LL;
    bf16*  sb     = (bf16*)Sr;
    bf16*  embT   = (bf16*)(Sr + 33554432LL);
    float* attn   = (float*)Sr;                  // (B,960q,960kv) fp32
    bf16*  probsT = (bf16*)(Sr + 29491200LL);    // (B,960kv,960q) bf16
    bf16*  probsP = (bf16*)(Sr + 44236800LL);    // (B,c,960) bf16
    bf16*  pbuf   = (bf16*)(Sr + 52101120LL);    // (B,960q,960kv) bf16
    bf16*  wb     = (bf16*)(ws + 255852544LL);
    float* part   = (float*)(ws + 260931584LL);
    float* stats  = (float*)(ws + 260939776LL);

    const dim3 blk(256);
    const float scale = (float)(1.0 / sqrt((double)KVC));
    const int CNl[4] = {64, 128, 256, 512};
    const int CSl[4] = {0, 64, 192, 448};
    const i64 wmOff[4] = {1843200, 1847296, 1863680, 1929216};
    const i64 wpOff[4] = {2191360, 2195456, 2211840, 2277376};

    // ---- weights -> bf16 --------------------------------------------------
    cvt_weights<<<2480, blk, 0, stream>>>(wmk, wmv,
        (const float*)d_in[5], (const float*)d_in[8],
        (const float*)d_in[11], (const float*)d_in[14],
        (const float*)d_in[7], (const float*)d_in[10],
        (const float*)d_in[13], (const float*)d_in[16], wb);

    // ---- emb_all^T (bf16) -> Q -------------------------------------------
    transpose_to_bt<float><<<dim3(64, 15, BATCH), blk, 0, stream>>>(emb_all, Q, KVC);

    // ---- K path: k = l2norm(dw3x3(wmk . emb_all)) (conv+norm fused) ------
    gemm_bt<bf16><<<dim3(32, 8, BATCH), blk, 0, stream>>>(
        wb, KVC, 0, Q, KVC, (i64)HW * KVC, sb, HW, (i64)KVC * HW,
        KVC, HW, KVC, 1.0f);
    dw3x3_fused<true><<<BATCH * KVC, blk, 0, stream>>>(sb, wk, kb, KVC);

    // ---- V path: v = dw3x3(wmv . emb_all); vT = v^T ----------------------
    gemm_bt<bf16><<<dim3(32, 8, BATCH), blk, 0, stream>>>(
        wb + 921600, KVC, 0, Q, KVC, (i64)HW * KVC, sb, HW, (i64)KVC * HW,
        KVC, HW, KVC, 1.0f);
    dw3x3_fused<false><<<BATCH * KVC, blk, 0, stream>>>(sb, wv, Q, KVC); // vb in Q
    transpose_to_bt<bf16><<<dim3(64, 15, BATCH), blk, 0, stream>>>(Q, vT, KVC);

    // ---- all q's into concat buffer (Q); gconv+l2norm fused --------------
    for (int i = 0; i < 4; ++i) {
        const int c = CNl[i], cs = CSl[i];
        transpose_to_bt<float><<<dim3(64, c / 64, BATCH), blk, 0, stream>>>(
            emb[i], embT, c);
        gemm_bt<bf16><<<dim3(32, (c + 127) / 128, BATCH), blk, 0, stream>>>(
            wb + wmOff[i], c, 0, embT, c, (i64)HW * c, sb, HW, (i64)c * HW,
            c, HW, c, 1.0f);
        gconv3x3_fused<<<BATCH * (c / 2), blk, 0, stream>>>(sb, wq[i], Q, c, cs);
    }

    // ---- merged attention scores: attn = scale * Qall . K^T --------------
    // (M=960 q-rows, N=960 kv-cols, K=4096) -> softmax axis contiguous
    gemm_bt<float><<<dim3(8, 8, BATCH), blk, 0, stream>>>(
        Q, HW, (i64)KVC * HW, kb, HW, (i64)KVC * HW, attn, KVC, (i64)KVC * KVC,
        KVC, KVC, HW, scale);

    // ---- per-branch instance-norm stats + row softmax + transpose --------
    inorm_partial<<<dim3(BATCH, 32, 4), blk, 0, stream>>>(attn, part);
    inorm_finish<<<dim3(BATCH, 4), 64, 0, stream>>>(part, stats);
    softmax_rows<<<dim3(KVC, BATCH), blk, 0, stream>>>(attn, pbuf, stats);
    transpose_sq<<<dim3(15, 15, BATCH), blk, 0, stream>>>(pbuf, probsT);

    // ---- per branch: probsP = wp . probs ; out = probsP . v --------------
    i64 ooff = 0;
    for (int i = 0; i < 4; ++i) {
        const int c = CNl[i], cs = CSl[i];
        gemm_bt<bf16><<<dim3(8, (c + 127) / 128, BATCH), blk, 0, stream>>>(
            wb + wpOff[i], c, 0, probsT + cs, KVC, (i64)KVC * KVC,
            probsP, KVC, (i64)c * KVC, c, KVC, c, 1.0f);
        gemm_bt<float><<<dim3(32, (c + 127) / 128, BATCH), blk, 0, stream>>>(
            probsP, KVC, (i64)c * KVC, vT, KVC, (i64)HW * KVC,
            out + ooff, HW, (i64)c * HW, c, HW, KVC, 1.0f);
        ooff += (i64)BATCH * c * HW;
    }
}

// Round 7
// 1021.448 us; speedup vs baseline: 2.8532x; 1.0202x over previous
//
#include <hip/hip_runtime.h>
#include <hip/hip_bf16.h>
#include <math.h>

typedef long long i64;
typedef __hip_bfloat16 bf16;

#define HW 4096
#define KVC 960
#define BATCH 8

using bf8 = __attribute__((ext_vector_type(8))) short;   // 8 bf16 (4 VGPRs)
using f32x4 = __attribute__((ext_vector_type(4))) float; // MFMA accum

__device__ __forceinline__ float bf2f(unsigned short u) {
    union { unsigned int i; float f; } c; c.i = ((unsigned int)u) << 16; return c.f;
}
__device__ __forceinline__ float tof(bf16 v) { return __bfloat162float(v); }
__device__ __forceinline__ unsigned short f2bs(float f) {
    bf16 h = __float2bfloat16(f); return *reinterpret_cast<unsigned short*>(&h);
}
__device__ __forceinline__ unsigned short tobs(float f) { return f2bs(f); }
__device__ __forceinline__ unsigned short tobs(bf16 v) { return *reinterpret_cast<unsigned short*>(&v); }
__device__ __forceinline__ void store1(float* p, float v) { *p = v; }
__device__ __forceinline__ void store1(bf16* p, float v) { *p = __float2bfloat16(v); }

// async global->LDS, 16B per lane. LDS dest is wave-uniform base + lane*16.
__device__ __forceinline__ void gl_lds16(const void* g, void* l) {
    __builtin_amdgcn_global_load_lds(
        (const __attribute__((address_space(1))) void*)g,
        (__attribute__((address_space(3))) void*)l,
        16, 0, 0);
}

// ---------------------------------------------------------------------------
// MFMA GEMM (4-wave): C[bz] = alpha * A[bz] * B[bz]^T
// A: (M,K) bf16 row-major (lda). B: (N,K) bf16 row-major (ldb). C: (M,N)
// fp32/bf16 (ldc). K%32==0. Tile 128x128, BK=32, 4 waves, wave = 64x64 via
// 4x4 mfma_f32_16x16x32_bf16. For LARGE grids (>= ~2048 blocks).
// ---------------------------------------------------------------------------
template<typename TC>
__global__ __launch_bounds__(256)
void gemm_bt(const bf16* __restrict__ A, int lda, i64 aBatch,
             const bf16* __restrict__ B, int ldb, i64 bBatch,
             TC* __restrict__ C, int ldc, i64 cBatch,
             int M, int N, int K, float alpha)
{
    __shared__ __align__(16) short As[128 * 32];
    __shared__ __align__(16) short Bs[128 * 32];

    const int bz = blockIdx.z;
    const int m0 = blockIdx.y * 128;
    const int n0 = blockIdx.x * 128;
    const int tid  = threadIdx.x;
    const int lane = tid & 63;
    const int wave = tid >> 6;
    const int wm = (wave & 1) * 64;
    const int wn = (wave >> 1) * 64;
    const int quad = lane >> 4;
    const int l16  = lane & 15;

    const bf16* Ab = A + (i64)bz * aBatch;
    const bf16* Bb = B + (i64)bz * bBatch;

    const int srow = lane >> 2;
    const int scol = (lane & 3) * 8;

    int ar0 = m0 + wave * 16 + srow;       if (ar0 >= M) ar0 = M - 1;
    int ar1 = m0 + 64 + wave * 16 + srow;  if (ar1 >= M) ar1 = M - 1;
    int br0 = n0 + wave * 16 + srow;       if (br0 >= N) br0 = N - 1;
    int br1 = n0 + 64 + wave * 16 + srow;  if (br1 >= N) br1 = N - 1;
    const bf16* pa0 = Ab + (i64)ar0 * lda + scol;
    const bf16* pa1 = Ab + (i64)ar1 * lda + scol;
    const bf16* pb0 = Bb + (i64)br0 * ldb + scol;
    const bf16* pb1 = Bb + (i64)br1 * ldb + scol;

    short* la0 = As + wave * 512;
    short* la1 = As + 2048 + wave * 512;
    short* lb0 = Bs + wave * 512;
    short* lb1 = Bs + 2048 + wave * 512;

    f32x4 acc[4][4] = {};

    for (int k0 = 0; k0 < K; k0 += 32) {
        gl_lds16(pa0 + k0, la0);
        gl_lds16(pa1 + k0, la1);
        gl_lds16(pb0 + k0, lb0);
        gl_lds16(pb1 + k0, lb1);
        __syncthreads();

        bf8 af[4], bfr[4];
        #pragma unroll
        for (int mt = 0; mt < 4; ++mt)
            af[mt] = *(const bf8*)(As + (wm + mt * 16 + l16) * 32 + quad * 8);
        #pragma unroll
        for (int nt = 0; nt < 4; ++nt)
            bfr[nt] = *(const bf8*)(Bs + (wn + nt * 16 + l16) * 32 + quad * 8);
        #pragma unroll
        for (int mt = 0; mt < 4; ++mt)
            #pragma unroll
            for (int nt = 0; nt < 4; ++nt)
                acc[mt][nt] = __builtin_amdgcn_mfma_f32_16x16x32_bf16(
                    af[mt], bfr[nt], acc[mt][nt], 0, 0, 0);
        __syncthreads();
    }

    const i64 cb = (i64)bz * cBatch;
    #pragma unroll
    for (int mt = 0; mt < 4; ++mt) {
        #pragma unroll
        for (int r = 0; r < 4; ++r) {
            const int row = m0 + wm + mt * 16 + quad * 4 + r;
            if (row >= M) continue;
            const i64 rb = cb + (i64)row * ldc;
            #pragma unroll
            for (int nt = 0; nt < 4; ++nt) {
                const int col = n0 + wn + nt * 16 + l16;
                if (col < N) store1(C + rb + col, alpha * acc[mt][nt][r]);
            }
        }
    }
}

// ---------------------------------------------------------------------------
// MFMA GEMM (8-wave, 512 threads): same math, tile 128x128, BK=32.
// Waves 2(M) x 4(N); each wave 64x32 via 4x2 MFMA -> 2x the resident waves
// per block. For SMALL grids (< ~2048 blocks) that are occupancy-starved
// with 4-wave blocks (attention gemm: 512 blocks -> 20% occ measured).
// Staging: one gl_lds16 per thread per operand (512 x 16B = full 8KB tile).
// ---------------------------------------------------------------------------
template<typename TC>
__global__ __launch_bounds__(512)
void gemm_bt8(const bf16* __restrict__ A, int lda, i64 aBatch,
              const bf16* __restrict__ B, int ldb, i64 bBatch,
              TC* __restrict__ C, int ldc, i64 cBatch,
              int M, int N, int K, float alpha)
{
    __shared__ __align__(16) short As[128 * 32];
    __shared__ __align__(16) short Bs[128 * 32];

    const int bz = blockIdx.z;
    const int m0 = blockIdx.y * 128;
    const int n0 = blockIdx.x * 128;
    const int tid  = threadIdx.x;
    const int lane = tid & 63;
    const int wave = tid >> 6;          // 0..7
    const int wm = (wave & 1) * 64;     // wave tile: 64 rows
    const int wn = (wave >> 1) * 32;    //            32 cols
    const int quad = lane >> 4;
    const int l16  = lane & 15;

    const bf16* Ab = A + (i64)bz * aBatch;
    const bf16* Bb = B + (i64)bz * bBatch;

    const int srow = lane >> 2;         // 0..15 within wave's 16-row group
    const int scol = (lane & 3) * 8;    // bf16 elems (16B chunk)

    int ar = m0 + wave * 16 + srow;  if (ar >= M) ar = M - 1;
    int br = n0 + wave * 16 + srow;  if (br >= N) br = N - 1;
    const bf16* pa = Ab + (i64)ar * lda + scol;
    const bf16* pb = Bb + (i64)br * ldb + scol;

    short* la = As + wave * 512;        // wave-uniform base + lane*16B
    short* lb = Bs + wave * 512;

    f32x4 acc[4][2] = {};

    for (int k0 = 0; k0 < K; k0 += 32) {
        gl_lds16(pa + k0, la);
        gl_lds16(pb + k0, lb);
        __syncthreads();

        bf8 af[4], bfr[2];
        #pragma unroll
        for (int mt = 0; mt < 4; ++mt)
            af[mt] = *(const bf8*)(As + (wm + mt * 16 + l16) * 32 + quad * 8);
        #pragma unroll
        for (int nt = 0; nt < 2; ++nt)
            bfr[nt] = *(const bf8*)(Bs + (wn + nt * 16 + l16) * 32 + quad * 8);
        #pragma unroll
        for (int mt = 0; mt < 4; ++mt)
            #pragma unroll
            for (int nt = 0; nt < 2; ++nt)
                acc[mt][nt] = __builtin_amdgcn_mfma_f32_16x16x32_bf16(
                    af[mt], bfr[nt], acc[mt][nt], 0, 0, 0);
        __syncthreads();
    }

    const i64 cb = (i64)bz * cBatch;
    #pragma unroll
    for (int mt = 0; mt < 4; ++mt) {
        #pragma unroll
        for (int r = 0; r < 4; ++r) {
            const int row = m0 + wm + mt * 16 + quad * 4 + r;
            if (row >= M) continue;
            const i64 rb = cb + (i64)row * ldc;
            #pragma unroll
            for (int nt = 0; nt < 2; ++nt) {
                const int col = n0 + wn + nt * 16 + l16;
                if (col < N) store1(C + rb + col, alpha * acc[mt][nt][r]);
            }
        }
    }
}

// ---------------------------------------------------------------------------
// Tiled transpose + convert: in (BATCH, C, 4096) (fp32 or bf16) ->
// out (BATCH, 4096, C) bf16. C % 64 == 0. 64x64 tiles, pad 66 shorts.
// ---------------------------------------------------------------------------
template<typename T>
__global__ __launch_bounds__(256)
void transpose_to_bt(const T* __restrict__ in, bf16* __restrict__ outT, int C)
{
    __shared__ unsigned short t[64][66];
    const int b  = blockIdx.z;
    const int n0 = blockIdx.x * 64;   // HW dim
    const int c0 = blockIdx.y * 64;   // C dim
    const int tx = threadIdx.x & 63, ty = threadIdx.x >> 6;
    const T* ip = in + ((i64)b * C + c0) * (i64)HW + n0;
    #pragma unroll
    for (int i = 0; i < 16; ++i) {
        const int r = ty + i * 4;
        t[r][tx] = tobs(ip[(i64)r * HW + tx]);
    }
    __syncthreads();
    bf16* op = outT + ((i64)b * HW + n0) * (i64)C + c0;
    #pragma unroll
    for (int i = 0; i < 16; ++i) {
        const int r = ty + i * 4;
        *(unsigned short*)(op + (i64)r * C + tx) = t[tx][r];
    }
}

// ---------------------------------------------------------------------------
// Square bf16 transpose: in (BATCH, 960, 960) -> out (BATCH, 960, 960)^T.
// ---------------------------------------------------------------------------
__global__ __launch_bounds__(256)
void transpose_sq(const bf16* __restrict__ in, bf16* __restrict__ out)
{
    __shared__ unsigned short t[64][66];
    const int b  = blockIdx.z;
    const int r0 = blockIdx.y * 64;
    const int c0 = blockIdx.x * 64;
    const int tx = threadIdx.x & 63, ty = threadIdx.x >> 6;
    const bf16* ip = in + ((i64)b * KVC + r0) * KVC + c0;
    #pragma unroll
    for (int i = 0; i < 16; ++i) {
        const int r = ty + i * 4;
        t[r][tx] = tobs(ip[(i64)r * KVC + tx]);
    }
    __syncthreads();
    bf16* op = out + ((i64)b * KVC + c0) * KVC + r0;
    #pragma unroll
    for (int i = 0; i < 16; ++i) {
        const int r = ty + i * 4;
        *(unsigned short*)(op + (i64)r * KVC + tx) = t[tx][r];
    }
}

// ---------------------------------------------------------------------------
// One-shot fp32 -> bf16 conversion of all 10 weight tensors into wb.
// ---------------------------------------------------------------------------
__global__ __launch_bounds__(256)
void cvt_weights(const float* __restrict__ s0, const float* __restrict__ s1,
                 const float* __restrict__ s2, const float* __restrict__ s3,
                 const float* __restrict__ s4, const float* __restrict__ s5,
                 const float* __restrict__ s6, const float* __restrict__ s7,
                 const float* __restrict__ s8, const float* __restrict__ s9,
                 bf16* __restrict__ wb)
{
    const int i = (blockIdx.x * 256 + threadIdx.x) * 4;
    if (i >= 2539520) return;
    const float* src; int off;
    if      (i <  921600) { src = s0; off = 0;       }
    else if (i < 1843200) { src = s1; off = 921600;  }
    else if (i < 1847296) { src = s2; off = 1843200; }
    else if (i < 1863680) { src = s3; off = 1847296; }
    else if (i < 1929216) { src = s4; off = 1863680; }
    else if (i < 2191360) { src = s5; off = 1929216; }
    else if (i < 2195456) { src = s6; off = 2191360; }
    else if (i < 2211840) { src = s7; off = 2195456; }
    else if (i < 2277376) { src = s8; off = 2211840; }
    else                  { src = s9; off = 2277376; }
    const float4 v = *(const float4*)(src + (i - off));
    ushort4 o;
    o.x = f2bs(v.x); o.y = f2bs(v.y); o.z = f2bs(v.z); o.w = f2bs(v.w);
    *(ushort4*)((unsigned short*)wb + i) = o;
}

// ---------------------------------------------------------------------------
// Fused depthwise 3x3 SAME (+ optional per-image L2 normalize).
// One block per (b,c) 64x64 image, staged via global_load_lds; 4x4 reg tile.
// ---------------------------------------------------------------------------
template<bool NORM>
__global__ __launch_bounds__(256)
void dw3x3_fused(const bf16* __restrict__ in, const float* __restrict__ w,
                 bf16* __restrict__ out, int C)
{
    __shared__ __align__(16) unsigned short img[4096];
    __shared__ float red[4];
    __shared__ float sinv;
    const int bc = blockIdx.x;
    const int c = bc % C;
    const int tid = threadIdx.x;
    const int lane = tid & 63, wave = tid >> 6;
    const bf16* ip = in + (i64)bc * HW;
    gl_lds16(ip + wave * 512 + lane * 8, img + wave * 512);
    gl_lds16(ip + (4 + wave) * 512 + lane * 8, img + (4 + wave) * 512);

    const float* wp9 = w + c * 9;
    float wr[9];
    #pragma unroll
    for (int i = 0; i < 9; ++i) wr[i] = wp9[i];
    __syncthreads();

    const int x0 = (tid & 15) * 4, y0 = (tid >> 4) * 4;
    float fin[6][6];
    #pragma unroll
    for (int r = 0; r < 6; ++r) {
        const int yy = y0 - 1 + r;
        const int yc = (yy < 0) ? 0 : (yy > 63 ? 63 : yy);
        const bool yok = (yy >= 0) && (yy <= 63);
        #pragma unroll
        for (int cc = 0; cc < 6; ++cc) {
            const int xx = x0 - 1 + cc;
            const int xc = (xx < 0) ? 0 : (xx > 63 ? 63 : xx);
            const float v = bf2f(img[yc * 64 + xc]);
            fin[r][cc] = (yok && xx >= 0 && xx <= 63) ? v : 0.f;
        }
    }

    float o[4][4];
    float ss = 0.f;
    #pragma unroll
    for (int r = 0; r < 4; ++r) {
        #pragma unroll
        for (int cc = 0; cc < 4; ++cc) {
            float s = 0.f;
            #pragma unroll
            for (int dy = 0; dy < 3; ++dy)
                #pragma unroll
                for (int dx = 0; dx < 3; ++dx)
                    s = fmaf(wr[dy * 3 + dx], fin[r + dy][cc + dx], s);
            o[r][cc] = s;
            ss = fmaf(s, s, ss);
        }
    }

    float inv = 1.f;
    if (NORM) {
        #pragma unroll
        for (int off = 32; off > 0; off >>= 1) ss += __shfl_down(ss, off);
        const int wid = tid >> 6;
        if (lane == 0) red[wid] = ss;
        __syncthreads();
        if (tid == 0) {
            const float t = red[0] + red[1] + red[2] + red[3];
            sinv = 1.0f / fmaxf(sqrtf(t), 1e-12f);
        }
        __syncthreads();
        inv = sinv;
    }

    bf16* op = out + (i64)bc * HW;
    #pragma unroll
    for (int r = 0; r < 4; ++r) {
        ushort4 pk;
        pk.x = f2bs(o[r][0] * inv);
        pk.y = f2bs(o[r][1] * inv);
        pk.z = f2bs(o[r][2] * inv);
        pk.w = f2bs(o[r][3] * inv);
        *(ushort4*)(op + (y0 + r) * 64 + x0) = pk;
    }
}

// ---------------------------------------------------------------------------
// Fused grouped 3x3 SAME (groups=C/2, 2in/2out) + per-out-channel L2 norm.
// One block per (b, group); writes (b,960,hw) concat buffer at cstart.
// ---------------------------------------------------------------------------
__global__ __launch_bounds__(256)
void gconv3x3_fused(const bf16* __restrict__ in, const float* __restrict__ w,
                    bf16* __restrict__ outAll, int C, int cstart)
{
    __shared__ __align__(16) unsigned short img[8192];
    __shared__ float red[2][4];
    __shared__ float sinv[2];
    const int nb = C >> 1;
    const int b = blockIdx.x / nb;
    const int g = blockIdx.x % nb;
    const int tid = threadIdx.x, lane = tid & 63, wave = tid >> 6;
    const bf16* ip = in + ((i64)b * C + 2 * g) * HW;
    #pragma unroll
    for (int it = 0; it < 4; ++it)
        gl_lds16(ip + (it * 4 + wave) * 512 + lane * 8, img + (it * 4 + wave) * 512);

    const float* wp = w + g * 36;
    float wr[36];
    #pragma unroll
    for (int i = 0; i < 36; ++i) wr[i] = wp[i];
    __syncthreads();

    const int x0 = (tid & 15) * 4, y0 = (tid >> 4) * 4;
    float fin[2][6][6];
    #pragma unroll
    for (int ic = 0; ic < 2; ++ic) {
        #pragma unroll
        for (int r = 0; r < 6; ++r) {
            const int yy = y0 - 1 + r;
            const int yc = (yy < 0) ? 0 : (yy > 63 ? 63 : yy);
            const bool yok = (yy >= 0) && (yy <= 63);
            #pragma unroll
            for (int cc = 0; cc < 6; ++cc) {
                const int xx = x0 - 1 + cc;
                const int xc = (xx < 0) ? 0 : (xx > 63 ? 63 : xx);
                const float v = bf2f(img[ic * 4096 + yc * 64 + xc]);
                fin[ic][r][cc] = (yok && xx >= 0 && xx <= 63) ? v : 0.f;
            }
        }
    }

    float o[2][4][4];
    float ss0 = 0.f, ss1 = 0.f;
    #pragma unroll
    for (int oc = 0; oc < 2; ++oc) {
        #pragma unroll
        for (int r = 0; r < 4; ++r) {
            #pragma unroll
            for (int cc = 0; cc < 4; ++cc) {
                float s = 0.f;
                #pragma unroll
                for (int ic = 0; ic < 2; ++ic)
                    #pragma unroll
                    for (int dy = 0; dy < 3; ++dy)
                        #pragma unroll
                        for (int dx = 0; dx < 3; ++dx)
                            s = fmaf(wr[oc * 18 + ic * 9 + dy * 3 + dx],
                                     fin[ic][r + dy][cc + dx], s);
                o[oc][r][cc] = s;
                if (oc == 0) ss0 = fmaf(s, s, ss0); else ss1 = fmaf(s, s, ss1);
            }
        }
    }

    #pragma unroll
    for (int off = 32; off > 0; off >>= 1) {
        ss0 += __shfl_down(ss0, off);
        ss1 += __shfl_down(ss1, off);
    }
    const int wid = tid >> 6;
    if (lane == 0) { red[0][wid] = ss0; red[1][wid] = ss1; }
    __syncthreads();
    if (tid == 0) {
        const float t0 = red[0][0] + red[0][1] + red[0][2] + red[0][3];
        const float t1 = red[1][0] + red[1][1] + red[1][2] + red[1][3];
        sinv[0] = 1.0f / fmaxf(sqrtf(t0), 1e-12f);
        sinv[1] = 1.0f / fmaxf(sqrtf(t1), 1e-12f);
    }
    __syncthreads();

    #pragma unroll
    for (int oc = 0; oc < 2; ++oc) {
        const float inv = sinv[oc];
        bf16* op = outAll + ((i64)b * KVC + cstart + 2 * g + oc) * HW;
        #pragma unroll
        for (int r = 0; r < 4; ++r) {
            ushort4 pk;
            pk.x = f2bs(o[oc][r][0] * inv);
            pk.y = f2bs(o[oc][r][1] * inv);
            pk.z = f2bs(o[oc][r][2] * inv);
            pk.w = f2bs(o[oc][r][3] * inv);
            *(ushort4*)(op + (y0 + r) * 64 + x0) = pk;
        }
    }
}

// ---------------------------------------------------------------------------
// Instance-norm stats over attn (BATCH, 960 q-rows, 960 kv-cols) fp32.
// Branch br = q-rows [CS,CS+c): one CONTIGUOUS c*960-float range per (b,br).
// ---------------------------------------------------------------------------
__global__ __launch_bounds__(256)
void inorm_partial(const float* __restrict__ a, float* __restrict__ part)
{
    const int b = blockIdx.x, ch = blockIdx.y, br = blockIdx.z;
    const int CC[4] = {64, 128, 256, 512};
    const int CS[4] = {0, 64, 192, 448};
    const int c = CC[br];
    const int n4 = c * 30 / 4;
    const float4* p = (const float4*)(a + (i64)b * (KVC * KVC)
                                        + (i64)CS[br] * KVC) + (i64)ch * n4;
    float s = 0.f, s2 = 0.f;
    for (int i = threadIdx.x; i < n4; i += 256) {
        const float4 v = p[i];
        s += v.x + v.y + v.z + v.w;
        s2 += v.x * v.x + v.y * v.y + v.z * v.z + v.w * v.w;
    }
    #pragma unroll
    for (int o = 32; o > 0; o >>= 1) { s += __shfl_down(s, o); s2 += __shfl_down(s2, o); }
    __shared__ float r1[4], r2[4];
    const int lane = threadIdx.x & 63, wid = threadIdx.x >> 6;
    if (lane == 0) { r1[wid] = s; r2[wid] = s2; }
    __syncthreads();
    if (threadIdx.x == 0) {
        part[((br * 8 + b) * 32 + ch) * 2 + 0] = r1[0] + r1[1] + r1[2] + r1[3];
        part[((br * 8 + b) * 32 + ch) * 2 + 1] = r2[0] + r2[1] + r2[2] + r2[3];
    }
}

__global__ __launch_bounds__(64)
void inorm_finish(const float* __restrict__ part, float* __restrict__ stats)
{
    const int b = blockIdx.x, br = blockIdx.y;
    const int i = threadIdx.x;
    float s = 0.f, s2 = 0.f;
    if (i < 32) {
        s  = part[((br * 8 + b) * 32 + i) * 2 + 0];
        s2 = part[((br * 8 + b) * 32 + i) * 2 + 1];
    }
    #pragma unroll
    for (int o = 16; o > 0; o >>= 1) { s += __shfl_down(s, o); s2 += __shfl_down(s2, o); }
    if (i == 0) {
        const int CC[4] = {64, 128, 256, 512};
        const float n = (float)(CC[br] * KVC);
        const float mu = s / n;
        const float var = s2 / n - mu * mu;
        stats[(br * 8 + b) * 2 + 0] = mu;
        stats[(br * 8 + b) * 2 + 1] = rsqrtf(var + 1e-5f);
    }
}

// ---------------------------------------------------------------------------
// Row softmax over attn (BATCH, 960 q-rows, 960 kv-cols contiguous) with
// per-branch instance-norm transform; writes probs bf16 same layout.
// ---------------------------------------------------------------------------
__global__ __launch_bounds__(256)
void softmax_rows(const float* __restrict__ a, bf16* __restrict__ p,
                  const float* __restrict__ stats)
{
    const int q = blockIdx.x, b = blockIdx.y;
    const int br = (q >= 448) ? 3 : (q >= 192) ? 2 : (q >= 64) ? 1 : 0;
    const float mu = stats[(br * 8 + b) * 2 + 0];
    const float rs = stats[(br * 8 + b) * 2 + 1];
    const i64 base = ((i64)b * KVC + q) * KVC;
    const int t = threadIdx.x;
    const bool act = t < 240;

    float x[4];
    float mx = -1e30f;
    if (act) {
        const float4 v = ((const float4*)(a + base))[t];
        x[0] = (v.x - mu) * rs; x[1] = (v.y - mu) * rs;
        x[2] = (v.z - mu) * rs; x[3] = (v.w - mu) * rs;
        mx = fmaxf(fmaxf(x[0], x[1]), fmaxf(x[2], x[3]));
    }
    __shared__ float red[4];
    __shared__ float bM, bS;
    const int lane = t & 63, wid = t >> 6;
    #pragma unroll
    for (int o = 32; o > 0; o >>= 1) mx = fmaxf(mx, __shfl_down(mx, o));
    if (lane == 0) red[wid] = mx;
    __syncthreads();
    if (t == 0) bM = fmaxf(fmaxf(red[0], red[1]), fmaxf(red[2], red[3]));
    __syncthreads();
    const float M = bM;

    float e[4];
    float se = 0.f;
    if (act) {
        #pragma unroll
        for (int j = 0; j < 4; ++j) { e[j] = __expf(x[j] - M); se += e[j]; }
    }
    #pragma unroll
    for (int o = 32; o > 0; o >>= 1) se += __shfl_down(se, o);
    if (lane == 0) red[wid] = se;
    __syncthreads();
    if (t == 0) bS = red[0] + red[1] + red[2] + red[3];
    __syncthreads();
    const float inv = 1.0f / bS;

    if (act) {
        ushort4 o4;
        o4.x = f2bs(e[0] * inv); o4.y = f2bs(e[1] * inv);
        o4.z = f2bs(e[2] * inv); o4.w = f2bs(e[3] * inv);
        ((ushort4*)((unsigned short*)p + base))[t] = o4;
    }
}

// ---------------------------------------------------------------------------
extern "C" void kernel_launch(void* const* d_in, const int* in_sizes, int n_in,
                              void* d_out, int out_size, void* d_ws, size_t ws_size,
                              hipStream_t stream)
{
    (void)in_sizes; (void)n_in; (void)out_size; (void)ws_size;

    const float* emb[4]  = {(const float*)d_in[0], (const float*)d_in[1],
                            (const float*)d_in[2], (const float*)d_in[3]};
    const float* emb_all = (const float*)d_in[4];
    const float* wq[4]   = {(const float*)d_in[6], (const float*)d_in[9],
                            (const float*)d_in[12], (const float*)d_in[15]};
    const float* wmk = (const float*)d_in[17];
    const float* wmv = (const float*)d_in[18];
    const float* wk  = (const float*)d_in[19];
    const float* wv  = (const float*)d_in[20];
    float* out = (float*)d_out;

    // ---- workspace regions (timeline-aliased) ----------------------------
    char* ws = (char*)d_ws;
    bf16*  kb     = (bf16*)ws;
    bf16*  vT     = (bf16*)(ws + 62914560LL);
    bf16*  Q      = (bf16*)(ws + 125829120LL);
    char*  Sr     = ws + 188743680LL;
    bf16*  sb     = (bf16*)Sr;
    bf16*  embT   = (bf16*)(Sr + 33554432LL);
    float* attn   = (float*)Sr;                  // (B,960q,960kv) fp32
    bf16*  probsT = (bf16*)(Sr + 29491200LL);    // (B,960kv,960q) bf16
    bf16*  probsP = (bf16*)(Sr + 44236800LL);    // (B,c,960) bf16
    bf16*  pbuf   = (bf16*)(Sr + 52101120LL);    // (B,960q,960kv) bf16
    bf16*  wb     = (bf16*)(ws + 255852544LL);
    float* part   = (float*)(ws + 260931584LL);
    float* stats  = (float*)(ws + 260939776LL);

    const dim3 blk(256);
    const dim3 blk8(512);
    const float scale = (float)(1.0 / sqrt((double)KVC));
    const int CNl[4] = {64, 128, 256, 512};
    const int CSl[4] = {0, 64, 192, 448};
    const i64 wmOff[4] = {1843200, 1847296, 1863680, 1929216};
    const i64 wpOff[4] = {2191360, 2195456, 2211840, 2277376};

    // ---- weights -> bf16 --------------------------------------------------
    cvt_weights<<<2480, blk, 0, stream>>>(wmk, wmv,
        (const float*)d_in[5], (const float*)d_in[8],
        (const float*)d_in[11], (const float*)d_in[14],
        (const float*)d_in[7], (const float*)d_in[10],
        (const float*)d_in[13], (const float*)d_in[16], wb);

    // ---- emb_all^T (bf16) -> Q -------------------------------------------
    transpose_to_bt<float><<<dim3(64, 15, BATCH), blk, 0, stream>>>(emb_all, Q, KVC);

    // ---- K path: k = l2norm(dw3x3(wmk . emb_all)) ------------------------
    gemm_bt<bf16><<<dim3(32, 8, BATCH), blk, 0, stream>>>(
        wb, KVC, 0, Q, KVC, (i64)HW * KVC, sb, HW, (i64)KVC * HW,
        KVC, HW, KVC, 1.0f);
    dw3x3_fused<true><<<BATCH * KVC, blk, 0, stream>>>(sb, wk, kb, KVC);

    // ---- V path: v = dw3x3(wmv . emb_all); vT = v^T ----------------------
    gemm_bt<bf16><<<dim3(32, 8, BATCH), blk, 0, stream>>>(
        wb + 921600, KVC, 0, Q, KVC, (i64)HW * KVC, sb, HW, (i64)KVC * HW,
        KVC, HW, KVC, 1.0f);
    dw3x3_fused<false><<<BATCH * KVC, blk, 0, stream>>>(sb, wv, Q, KVC); // vb in Q
    transpose_to_bt<bf16><<<dim3(64, 15, BATCH), blk, 0, stream>>>(Q, vT, KVC);

    // ---- all q's into concat buffer (Q); gconv+l2norm fused --------------
    for (int i = 0; i < 4; ++i) {
        const int c = CNl[i], cs = CSl[i];
        transpose_to_bt<float><<<dim3(64, c / 64, BATCH), blk, 0, stream>>>(
            emb[i], embT, c);
        gemm_bt8<bf16><<<dim3(32, (c + 127) / 128, BATCH), blk8, 0, stream>>>(
            wb + wmOff[i], c, 0, embT, c, (i64)HW * c, sb, HW, (i64)c * HW,
            c, HW, c, 1.0f);
        gconv3x3_fused<<<BATCH * (c / 2), blk, 0, stream>>>(sb, wq[i], Q, c, cs);
    }

    // ---- merged attention scores: attn = scale * Qall . K^T --------------
    // (M=960 q-rows, N=960 kv-cols, K=4096); 8-wave blocks for occupancy
    gemm_bt8<float><<<dim3(8, 8, BATCH), blk8, 0, stream>>>(
        Q, HW, (i64)KVC * HW, kb, HW, (i64)KVC * HW, attn, KVC, (i64)KVC * KVC,
        KVC, KVC, HW, scale);

    // ---- per-branch instance-norm stats + row softmax + transpose --------
    inorm_partial<<<dim3(BATCH, 32, 4), blk, 0, stream>>>(attn, part);
    inorm_finish<<<dim3(BATCH, 4), 64, 0, stream>>>(part, stats);
    softmax_rows<<<dim3(KVC, BATCH), blk, 0, stream>>>(attn, pbuf, stats);
    transpose_sq<<<dim3(15, 15, BATCH), blk, 0, stream>>>(pbuf, probsT);

    // ---- per branch: probsP = wp . probs ; out = probsP . v --------------
    i64 ooff = 0;
    for (int i = 0; i < 4; ++i) {
        const int c = CNl[i], cs = CSl[i];
        gemm_bt8<bf16><<<dim3(8, (c + 127) / 128, BATCH), blk8, 0, stream>>>(
            wb + wpOff[i], c, 0, probsT + cs, KVC, (i64)KVC * KVC,
            probsP, KVC, (i64)c * KVC, c, KVC, c, 1.0f);
        gemm_bt8<float><<<dim3(32, (c + 127) / 128, BATCH), blk8, 0, stream>>>(
            probsP, KVC, (i64)c * KVC, vT, KVC, (i64)HW * KVC,
            out + ooff, HW, (i64)c * HW, c, HW, KVC, 1.0f);
        ooff += (i64)BATCH * c * HW;
    }
}